// Round 1
// baseline (2628.585 us; speedup 1.0000x reference)
//
#include <hip/hip_runtime.h>
#include <math.h>

#define NB    2
#define NPTS  8192
#define NC    128
#define NKN   16
#define BN_EPS 1e-5f

// ---------------------------------------------------------------------------
// Kernel 1: q/k/v = W @ x + b, stored transposed as [b][n][c] for gathers.
// grid (NPTS/64, 3, NB), block 256
// ---------------------------------------------------------------------------
__global__ __launch_bounds__(256) void qkv_kernel(
    const float* __restrict__ x,
    const float* __restrict__ wq, const float* __restrict__ bq,
    const float* __restrict__ wk, const float* __restrict__ bk,
    const float* __restrict__ wv, const float* __restrict__ bv,
    float* __restrict__ qT, float* __restrict__ kT, float* __restrict__ vT)
{
    const int bb  = blockIdx.z;
    const int mat = blockIdx.y;
    const int i0  = blockIdx.x * 64;
    const float* __restrict__ w    = (mat == 0) ? wq : (mat == 1 ? wk : wv);
    const float* __restrict__ bias = (mat == 0) ? bq : (mat == 1 ? bk : bv);
    float* __restrict__ out        = (mat == 0) ? qT : (mat == 1 ? kT : vT);

    __shared__ float xs[128][68];   // pad 68: 16B-aligned rows, conflict-free
    for (int e = threadIdx.x; e < 128 * 64; e += 256) {
        int cin = e >> 6, ii = e & 63;
        xs[cin][ii] = x[(bb * NC + cin) * NPTS + i0 + ii];
    }
    __syncthreads();

    const int cbase  = (threadIdx.x & 31) * 4;   // 4 output channels
    const int iibase = (threadIdx.x >> 5) * 8;   // 8 points
    float acc[4][8];
    #pragma unroll
    for (int a = 0; a < 4; a++)
        #pragma unroll
        for (int b = 0; b < 8; b++) acc[a][b] = 0.0f;

    for (int cin = 0; cin < 128; cin++) {
        float4 xa = *(const float4*)&xs[cin][iibase];
        float4 xb = *(const float4*)&xs[cin][iibase + 4];
        float wr[4];
        #pragma unroll
        for (int a = 0; a < 4; a++) wr[a] = w[(cbase + a) * NC + cin];
        #pragma unroll
        for (int a = 0; a < 4; a++) {
            acc[a][0] += wr[a] * xa.x; acc[a][1] += wr[a] * xa.y;
            acc[a][2] += wr[a] * xa.z; acc[a][3] += wr[a] * xa.w;
            acc[a][4] += wr[a] * xb.x; acc[a][5] += wr[a] * xb.y;
            acc[a][6] += wr[a] * xb.z; acc[a][7] += wr[a] * xb.w;
        }
    }
    #pragma unroll
    for (int a = 0; a < 4; a++) {
        float bb_ = bias[cbase + a];
        #pragma unroll
        for (int b = 0; b < 8; b++)
            out[(bb * NPTS + i0 + iibase + b) * NC + cbase + a] = acc[a][b] + bb_;
    }
}

// ---------------------------------------------------------------------------
// Kernel 2: exact kNN-16. One thread per query, LDS-tiled candidates,
// per-thread 16-element max-heap kept in LDS (bank = f(tid) only).
// Distance formula bit-matches the reference: (sq_i + sq_j) - 2*dot, no FMA.
// grid (NPTS/256, NB), block 256
// ---------------------------------------------------------------------------
__global__ __launch_bounds__(256) void knn_kernel(
    const float* __restrict__ p,      // [NB][NPTS][3]
    int* __restrict__ knn_idx)        // [NB][NPTS][16]
{
    const int bb = blockIdx.y;
    const int t  = threadIdx.x;
    const int i  = blockIdx.x * 256 + t;

    __shared__ float px[2048], py[2048], pz[2048], sq[2048];
    __shared__ float hd[16 * 256];
    __shared__ int   hx[16 * 256];

    #pragma unroll
    for (int kk = 0; kk < 16; kk++) { hd[kk * 256 + t] = 3.4e38f; hx[kk * 256 + t] = 0; }

    const float qx = p[(bb * NPTS + i) * 3 + 0];
    const float qy = p[(bb * NPTS + i) * 3 + 1];
    const float qz = p[(bb * NPTS + i) * 3 + 2];
    const float sqi = __fadd_rn(__fadd_rn(__fmul_rn(qx, qx), __fmul_rn(qy, qy)),
                                __fmul_rn(qz, qz));

    for (int tile = 0; tile < NPTS / 2048; tile++) {
        const int base = tile * 2048;
        __syncthreads();   // previous tile's readers done before overwrite
        for (int e = t; e < 2048 * 3; e += 256) {
            float v = p[(bb * NPTS + base) * 3 + e];
            int j = e / 3;
            int d = e - j * 3;
            if (d == 0) px[j] = v; else if (d == 1) py[j] = v; else pz[j] = v;
        }
        __syncthreads();
        for (int j = t; j < 2048; j += 256)
            sq[j] = __fadd_rn(__fadd_rn(__fmul_rn(px[j], px[j]), __fmul_rn(py[j], py[j])),
                              __fmul_rn(pz[j], pz[j]));
        __syncthreads();

        #pragma unroll 4
        for (int j = 0; j < 2048; j++) {
            float dot = __fadd_rn(__fadd_rn(__fmul_rn(qx, px[j]), __fmul_rn(qy, py[j])),
                                  __fmul_rn(qz, pz[j]));
            float d2 = __fsub_rn(__fadd_rn(sqi, sq[j]), __fmul_rn(2.0f, dot));
            if (d2 < hd[t]) {      // strictly less: ties keep earlier index (matches top_k)
                int pos = 0;
                for (;;) {
                    int l = 2 * pos + 1;
                    if (l >= 16) break;
                    int r = l + 1;
                    float dl = hd[l * 256 + t];
                    float dr = (r < 16) ? hd[r * 256 + t] : -1.0f;
                    bool useR = (r < 16) && (dr > dl);
                    int   pb = useR ? r : l;
                    float db = useR ? dr : dl;
                    if (db > d2) {
                        hd[pos * 256 + t] = db;
                        hx[pos * 256 + t] = hx[pb * 256 + t];
                        pos = pb;
                    } else break;
                }
                hd[pos * 256 + t] = d2;
                hx[pos * 256 + t] = base + j;
            }
        }
    }
    #pragma unroll
    for (int kk = 0; kk < 16; kk++)
        knn_idx[(bb * NPTS + i) * 16 + kk] = hx[kk * 256 + t];
}

// ---------------------------------------------------------------------------
// Kernel 3: fused PE-MLP + attention MLP + softmax + weighted sum.
// 4 points/block (64 cols), 256 threads. a1/a2 share one swizzled LDS buffer.
// Thread tile: 2 channels x 16 cols (one full point -> softmax thread-local).
// grid (NPTS/4, NB), block 256
// ---------------------------------------------------------------------------
__global__ __launch_bounds__(256) void attn_kernel(
    const float* __restrict__ p,
    const float* __restrict__ qT, const float* __restrict__ kT, const float* __restrict__ vT,
    const int*   __restrict__ knn_idx,
    const float* __restrict__ pe_w1,
    const float* __restrict__ pe_bn_g, const float* __restrict__ pe_bn_b,
    const float* __restrict__ pe_bn_m, const float* __restrict__ pe_bn_v,
    const float* __restrict__ pe_w2, const float* __restrict__ pe_b2,
    const float* __restrict__ bn1g, const float* __restrict__ bn1b,
    const float* __restrict__ bn1m, const float* __restrict__ bn1v,
    const float* __restrict__ at_w1,
    const float* __restrict__ bn2g, const float* __restrict__ bn2b,
    const float* __restrict__ bn2m, const float* __restrict__ bn2v,
    const float* __restrict__ at_w2, const float* __restrict__ at_b2,
    float* __restrict__ y)
{
    const int bb = blockIdx.y;
    const int i0 = blockIdx.x * 4;
    const int t  = threadIdx.x;

    __shared__ float abuf[128][68];   // swizzled: (c,col) -> [c][4*((col>>2)^((c>>3)&7)) + (col&3)]
    __shared__ float hbuf[3][64];
    __shared__ int   nidx[64];
    __shared__ float qv[4][128];
    __shared__ float sc1[128], sh1[128], sc2[128], sh2[128];
    __shared__ float pw2t[3][128], pb2s[128], ab2s[128];

    // ---- phase 0a: params + neighbor indices ----
    if (t < 128) {
        int c = t;
        float s1 = bn1g[c] / sqrtf(bn1v[c] + BN_EPS);
        sc1[c] = s1; sh1[c] = bn1b[c] - bn1m[c] * s1;
        float s2 = bn2g[c] / sqrtf(bn2v[c] + BN_EPS);
        sc2[c] = s2; sh2[c] = bn2b[c] - bn2m[c] * s2;
        pw2t[0][c] = pe_w2[c * 3 + 0];
        pw2t[1][c] = pe_w2[c * 3 + 1];
        pw2t[2][c] = pe_w2[c * 3 + 2];
        pb2s[c] = pe_b2[c];
        ab2s[c] = at_b2[c];
    } else if (t < 192) {
        int e = t - 128;
        nidx[e] = knn_idx[(bb * NPTS + i0 + (e >> 4)) * 16 + (e & 15)];
    }
    __syncthreads();

    // ---- phase 0b: q rows + positional-encoding hidden layer ----
    for (int e = t; e < 512; e += 256) {
        int pidx = e >> 7, c = e & 127;
        qv[pidx][c] = qT[(bb * NPTS + i0 + pidx) * NC + c];
    }
    if (t < 64) {
        int pidx = t >> 4;
        int j = nidx[t];
        float pix = p[(bb * NPTS + i0 + pidx) * 3 + 0];
        float piy = p[(bb * NPTS + i0 + pidx) * 3 + 1];
        float piz = p[(bb * NPTS + i0 + pidx) * 3 + 2];
        float rx = p[(bb * NPTS + j) * 3 + 0] - pix;
        float ry = p[(bb * NPTS + j) * 3 + 1] - piy;
        float rz = p[(bb * NPTS + j) * 3 + 2] - piz;
        #pragma unroll
        for (int o = 0; o < 3; o++) {
            float hv = pe_w1[o * 3 + 0] * rx + pe_w1[o * 3 + 1] * ry + pe_w1[o * 3 + 2] * rz;
            float sc = pe_bn_g[o] / sqrtf(pe_bn_v[o] + BN_EPS);
            float sh = pe_bn_b[o] - pe_bn_m[o] * sc;
            hbuf[o][t] = fmaxf(hv * sc + sh, 0.0f);
        }
    }
    __syncthreads();

    // ---- phase 1: a1 = relu(bn1(q - gk + n_r)) into swizzled LDS ----
    for (int e = t; e < 2048; e += 256) {          // (c, col4) units
        int c = e & 127, col4 = e >> 7;
        int pidx = col4 >> 2;
        float qvr = qv[pidx][c];
        float s1 = sc1[c], b1 = sh1[c];
        float pw0 = pw2t[0][c], pw1 = pw2t[1][c], pw2v = pw2t[2][c], pb = pb2s[c];
        float ov[4];
        #pragma unroll
        for (int r = 0; r < 4; r++) {
            int col = col4 * 4 + r;
            int j = nidx[col];
            float gk = kT[(bb * NPTS + j) * NC + c];
            float nrv = pw0 * hbuf[0][col] + pw1 * hbuf[1][col] + pw2v * hbuf[2][col] + pb;
            float a = (qvr - gk + nrv) * s1 + b1;
            ov[r] = fmaxf(a, 0.0f);
        }
        *(float4*)&abuf[c][((col4 ^ ((c >> 3) & 7)) << 2)] =
            make_float4(ov[0], ov[1], ov[2], ov[3]);
    }
    __syncthreads();

    const int pp = t & 3;            // point within block
    const int c2 = (t >> 2) * 2;     // 2 output channels
    float acc[2][16];

    // ---- GEMM1: a2 = at_w1 @ a1 ----
    #pragma unroll
    for (int a = 0; a < 2; a++)
        #pragma unroll
        for (int kk = 0; kk < 16; kk++) acc[a][kk] = 0.0f;
    for (int cin = 0; cin < 128; cin++) {
        float w0 = at_w1[c2 * NC + cin];
        float w1 = at_w1[(c2 + 1) * NC + cin];
        int g = (cin >> 3) & 7;
        #pragma unroll
        for (int qq = 0; qq < 4; qq++) {
            int col4 = pp * 4 + qq;
            float4 av = *(const float4*)&abuf[cin][((col4 ^ g) << 2)];
            acc[0][qq * 4 + 0] += w0 * av.x; acc[0][qq * 4 + 1] += w0 * av.y;
            acc[0][qq * 4 + 2] += w0 * av.z; acc[0][qq * 4 + 3] += w0 * av.w;
            acc[1][qq * 4 + 0] += w1 * av.x; acc[1][qq * 4 + 1] += w1 * av.y;
            acc[1][qq * 4 + 2] += w1 * av.z; acc[1][qq * 4 + 3] += w1 * av.w;
        }
    }
    __syncthreads();   // all GEMM1 reads done before overwrite

    // ---- bn2 + relu, write a2 back into the same buffer ----
    #pragma unroll
    for (int a = 0; a < 2; a++) {
        int c = c2 + a;
        float s = sc2[c], bsh = sh2[c];
        int g = (c >> 3) & 7;
        #pragma unroll
        for (int qq = 0; qq < 4; qq++) {
            float v0 = fmaxf(acc[a][qq * 4 + 0] * s + bsh, 0.0f);
            float v1 = fmaxf(acc[a][qq * 4 + 1] * s + bsh, 0.0f);
            float v2 = fmaxf(acc[a][qq * 4 + 2] * s + bsh, 0.0f);
            float v3 = fmaxf(acc[a][qq * 4 + 3] * s + bsh, 0.0f);
            *(float4*)&abuf[c][(((pp * 4 + qq) ^ g) << 2)] = make_float4(v0, v1, v2, v3);
        }
    }
    __syncthreads();

    // ---- GEMM2: a3 = at_w2 @ a2 ----
    #pragma unroll
    for (int a = 0; a < 2; a++)
        #pragma unroll
        for (int kk = 0; kk < 16; kk++) acc[a][kk] = 0.0f;
    for (int cin = 0; cin < 128; cin++) {
        float w0 = at_w2[c2 * NC + cin];
        float w1 = at_w2[(c2 + 1) * NC + cin];
        int g = (cin >> 3) & 7;
        #pragma unroll
        for (int qq = 0; qq < 4; qq++) {
            int col4 = pp * 4 + qq;
            float4 av = *(const float4*)&abuf[cin][((col4 ^ g) << 2)];
            acc[0][qq * 4 + 0] += w0 * av.x; acc[0][qq * 4 + 1] += w0 * av.y;
            acc[0][qq * 4 + 2] += w0 * av.z; acc[0][qq * 4 + 3] += w0 * av.w;
            acc[1][qq * 4 + 0] += w1 * av.x; acc[1][qq * 4 + 1] += w1 * av.y;
            acc[1][qq * 4 + 2] += w1 * av.z; acc[1][qq * 4 + 3] += w1 * av.w;
        }
    }

    // ---- bias + softmax over k + weighted sum of n_v ----
    #pragma unroll
    for (int a = 0; a < 2; a++) {
        int c = c2 + a;
        float bias2 = ab2s[c];
        float m = -3.4e38f;
        #pragma unroll
        for (int kk = 0; kk < 16; kk++) { acc[a][kk] += bias2; m = fmaxf(m, acc[a][kk]); }
        float ex[16];
        float s = 0.0f;
        #pragma unroll
        for (int kk = 0; kk < 16; kk++) { ex[kk] = expf(acc[a][kk] - m); s += ex[kk]; }
        float invs = 1.0f / s;
        float pw0 = pw2t[0][c], pw1 = pw2t[1][c], pw2v = pw2t[2][c], pb = pb2s[c];
        float ysum = 0.0f;
        #pragma unroll
        for (int kk = 0; kk < 16; kk++) {
            int col = pp * 16 + kk;
            int j = nidx[col];
            float gv = vT[(bb * NPTS + j) * NC + c];
            float nrv = pw0 * hbuf[0][col] + pw1 * hbuf[1][col] + pw2v * hbuf[2][col] + pb;
            ysum += (gv + nrv) * (ex[kk] * invs);
        }
        y[(bb * NC + c) * NPTS + i0 + pp] = ysum;
    }
}

// ---------------------------------------------------------------------------
extern "C" void kernel_launch(void* const* d_in, const int* in_sizes, int n_in,
                              void* d_out, int out_size, void* d_ws, size_t ws_size,
                              hipStream_t stream) {
    const float* p     = (const float*)d_in[0];
    const float* x     = (const float*)d_in[1];
    const float* wq    = (const float*)d_in[2];
    const float* bq    = (const float*)d_in[3];
    const float* wk    = (const float*)d_in[4];
    const float* bk    = (const float*)d_in[5];
    const float* wv    = (const float*)d_in[6];
    const float* bv    = (const float*)d_in[7];
    const float* pe_w1 = (const float*)d_in[8];
    const float* pe_bn_g = (const float*)d_in[9];
    const float* pe_bn_b = (const float*)d_in[10];
    const float* pe_bn_m = (const float*)d_in[11];
    const float* pe_bn_v = (const float*)d_in[12];
    const float* pe_w2 = (const float*)d_in[13];
    const float* pe_b2 = (const float*)d_in[14];
    const float* bn1g  = (const float*)d_in[15];
    const float* bn1b  = (const float*)d_in[16];
    const float* bn1m  = (const float*)d_in[17];
    const float* bn1v  = (const float*)d_in[18];
    const float* at_w1 = (const float*)d_in[19];
    const float* bn2g  = (const float*)d_in[20];
    const float* bn2b  = (const float*)d_in[21];
    const float* bn2m  = (const float*)d_in[22];
    const float* bn2v  = (const float*)d_in[23];
    const float* at_w2 = (const float*)d_in[24];
    const float* at_b2 = (const float*)d_in[25];
    float* out = (float*)d_out;

    // workspace layout (25 MB): qT | kT | vT  (each [NB][NPTS][NC] f32), then idx
    float* qT = (float*)d_ws;
    float* kT = qT + (size_t)NB * NPTS * NC;
    float* vT = kT + (size_t)NB * NPTS * NC;
    int*  idx = (int*)(vT + (size_t)NB * NPTS * NC);

    qkv_kernel<<<dim3(NPTS / 64, 3, NB), 256, 0, stream>>>(
        x, wq, bq, wk, bk, wv, bv, qT, kT, vT);
    knn_kernel<<<dim3(NPTS / 256, NB), 256, 0, stream>>>(p, idx);
    attn_kernel<<<dim3(NPTS / 4, NB), 256, 0, stream>>>(
        p, qT, kT, vT, idx,
        pe_w1, pe_bn_g, pe_bn_b, pe_bn_m, pe_bn_v, pe_w2, pe_b2,
        bn1g, bn1b, bn1m, bn1v, at_w1,
        bn2g, bn2b, bn2m, bn2v, at_w2, at_b2, out);
}

// Round 2
// 784.306 us; speedup vs baseline: 3.3515x; 3.3515x over previous
//
#include <hip/hip_runtime.h>
#include <math.h>

#define NB    2
#define NPTS  8192
#define NC    128
#define NKN   16
#define NSPLIT 8
#define CAND_PER_SPLIT (NPTS / NSPLIT)   // 1024
#define BN_EPS 1e-5f

// branchless stable sorted-insert into register arrays ld[16]/li[16]
// (ascending by dist; strict < keeps earlier-index entries first on ties,
// matching jax.lax.top_k stability)
#define INSERT16(DV, JV)                                             \
  if ((DV) < ld[15]) {                                               \
    ld[15] = (DV); li[15] = (JV);                                    \
    _Pragma("unroll")                                                \
    for (int s_ = 15; s_ > 0; s_--) {                                \
      bool sw_ = ld[s_] < ld[s_ - 1];                                \
      float da_ = ld[s_ - 1], db_ = ld[s_];                          \
      ld[s_ - 1] = sw_ ? db_ : da_;                                  \
      ld[s_]     = sw_ ? da_ : db_;                                  \
      int ia_ = li[s_ - 1], ib_ = li[s_];                            \
      li[s_ - 1] = sw_ ? ib_ : ia_;                                  \
      li[s_]     = sw_ ? ia_ : ib_;                                  \
    }                                                                \
  }

// ---------------------------------------------------------------------------
// Kernel 1: q/k/v = W @ x + b, stored transposed as [b][n][c] for gathers.
// grid (NPTS/64, 3, NB), block 256
// ---------------------------------------------------------------------------
__global__ __launch_bounds__(256) void qkv_kernel(
    const float* __restrict__ x,
    const float* __restrict__ wq, const float* __restrict__ bq,
    const float* __restrict__ wk, const float* __restrict__ bk,
    const float* __restrict__ wv, const float* __restrict__ bv,
    float* __restrict__ qT, float* __restrict__ kT, float* __restrict__ vT)
{
    const int bb  = blockIdx.z;
    const int mat = blockIdx.y;
    const int i0  = blockIdx.x * 64;
    const float* __restrict__ w    = (mat == 0) ? wq : (mat == 1 ? wk : wv);
    const float* __restrict__ bias = (mat == 0) ? bq : (mat == 1 ? bk : bv);
    float* __restrict__ out        = (mat == 0) ? qT : (mat == 1 ? kT : vT);

    __shared__ float xs[128][68];
    for (int e = threadIdx.x; e < 128 * 64; e += 256) {
        int cin = e >> 6, ii = e & 63;
        xs[cin][ii] = x[(bb * NC + cin) * NPTS + i0 + ii];
    }
    __syncthreads();

    const int cbase  = (threadIdx.x & 31) * 4;
    const int iibase = (threadIdx.x >> 5) * 8;
    float acc[4][8];
    #pragma unroll
    for (int a = 0; a < 4; a++)
        #pragma unroll
        for (int b = 0; b < 8; b++) acc[a][b] = 0.0f;

    for (int cin = 0; cin < 128; cin++) {
        float4 xa = *(const float4*)&xs[cin][iibase];
        float4 xb = *(const float4*)&xs[cin][iibase + 4];
        float wr[4];
        #pragma unroll
        for (int a = 0; a < 4; a++) wr[a] = w[(cbase + a) * NC + cin];
        #pragma unroll
        for (int a = 0; a < 4; a++) {
            acc[a][0] += wr[a] * xa.x; acc[a][1] += wr[a] * xa.y;
            acc[a][2] += wr[a] * xa.z; acc[a][3] += wr[a] * xa.w;
            acc[a][4] += wr[a] * xb.x; acc[a][5] += wr[a] * xb.y;
            acc[a][6] += wr[a] * xb.z; acc[a][7] += wr[a] * xb.w;
        }
    }
    #pragma unroll
    for (int a = 0; a < 4; a++) {
        float bb_ = bias[cbase + a];
        #pragma unroll
        for (int b = 0; b < 8; b++)
            out[(bb * NPTS + i0 + iibase + b) * NC + cbase + a] = acc[a][b] + bb_;
    }
}

// ---------------------------------------------------------------------------
// Kernel 2a: kNN phase A — partial top-16 per (query, candidate-split).
// grid (NPTS/256, NSPLIT, NB), block 256. One thread per query.
// Candidates staged as float4 (x,y,z,|p|^2) -> one ds_read_b128 broadcast each.
// Register-resident sorted-16, static indexing only.
// Distance formula bit-matches reference: (sq_i + sq_j) - 2*dot, no FMA.
// ---------------------------------------------------------------------------
__global__ __launch_bounds__(256) void knnA_kernel(
    const float* __restrict__ p,      // [NB][NPTS][3]
    float2* __restrict__ part)        // [NB][NSPLIT][NPTS][16] (dist, idx-bits)
{
    const int bb    = blockIdx.z;
    const int split = blockIdx.y;
    const int q0    = blockIdx.x * 256;
    const int t     = threadIdx.x;

    __shared__ float4 cand[CAND_PER_SPLIT];   // 16 KB

    const float* __restrict__ pc = p + ((size_t)bb * NPTS + split * CAND_PER_SPLIT) * 3;
    for (int j = t; j < CAND_PER_SPLIT; j += 256) {
        float cx = pc[j * 3 + 0];
        float cy = pc[j * 3 + 1];
        float cz = pc[j * 3 + 2];
        float s  = __fadd_rn(__fadd_rn(__fmul_rn(cx, cx), __fmul_rn(cy, cy)),
                             __fmul_rn(cz, cz));
        cand[j] = make_float4(cx, cy, cz, s);
    }
    __syncthreads();

    const int i = q0 + t;
    const float qx = p[((size_t)bb * NPTS + i) * 3 + 0];
    const float qy = p[((size_t)bb * NPTS + i) * 3 + 1];
    const float qz = p[((size_t)bb * NPTS + i) * 3 + 2];
    const float sqi = __fadd_rn(__fadd_rn(__fmul_rn(qx, qx), __fmul_rn(qy, qy)),
                                __fmul_rn(qz, qz));

    float ld[16];
    int   li[16];
    #pragma unroll
    for (int s = 0; s < 16; s++) { ld[s] = 3.4e38f; li[s] = 0; }

    const int jbase = split * CAND_PER_SPLIT;
    #pragma unroll 4
    for (int j = 0; j < CAND_PER_SPLIT; j++) {
        float4 c = cand[j];
        float dot = __fadd_rn(__fadd_rn(__fmul_rn(qx, c.x), __fmul_rn(qy, c.y)),
                              __fmul_rn(qz, c.z));
        float d2 = __fsub_rn(__fadd_rn(sqi, c.w), __fmul_rn(2.0f, dot));
        INSERT16(d2, jbase + j);
    }

    // write 16 (dist, idx) pairs as 8 float4 stores
    float2* __restrict__ row = part + (((size_t)bb * NSPLIT + split) * NPTS + i) * 16;
    #pragma unroll
    for (int s = 0; s < 16; s += 2) {
        float4 o = make_float4(ld[s], __int_as_float(li[s]),
                               ld[s + 1], __int_as_float(li[s + 1]));
        *(float4*)&row[s] = o;
    }
}

// ---------------------------------------------------------------------------
// Kernel 2b: kNN merge — fold NSPLIT partial sorted-16 lists into final 16.
// Processing splits in order + strict-< insert preserves (dist, index) order.
// grid (NB*NPTS/256), block 256. One thread per query.
// ---------------------------------------------------------------------------
__global__ __launch_bounds__(256) void knnM_kernel(
    const float2* __restrict__ part,
    int* __restrict__ knn_idx)        // [NB][NPTS][16]
{
    const int gid = blockIdx.x * 256 + threadIdx.x;   // 0 .. NB*NPTS-1
    const int bb  = gid >> 13;
    const int i   = gid & (NPTS - 1);

    float ld[16];
    int   li[16];
    #pragma unroll
    for (int s = 0; s < 16; s++) { ld[s] = 3.4e38f; li[s] = 0; }

    for (int sp = 0; sp < NSPLIT; sp++) {
        const float2* __restrict__ row =
            part + (((size_t)bb * NSPLIT + sp) * NPTS + i) * 16;
        #pragma unroll
        for (int s = 0; s < 16; s += 2) {
            float4 e = *(const float4*)&row[s];
            float d0 = e.x; int j0 = __float_as_int(e.y);
            float d1 = e.z; int j1 = __float_as_int(e.w);
            INSERT16(d0, j0);
            INSERT16(d1, j1);
        }
    }

    #pragma unroll
    for (int s = 0; s < 16; s++)
        knn_idx[(size_t)gid * 16 + s] = li[s];
}

// ---------------------------------------------------------------------------
// Kernel 3: fused PE-MLP + attention MLP + softmax + weighted sum.
// (unchanged from round 1)
// ---------------------------------------------------------------------------
__global__ __launch_bounds__(256) void attn_kernel(
    const float* __restrict__ p,
    const float* __restrict__ qT, const float* __restrict__ kT, const float* __restrict__ vT,
    const int*   __restrict__ knn_idx,
    const float* __restrict__ pe_w1,
    const float* __restrict__ pe_bn_g, const float* __restrict__ pe_bn_b,
    const float* __restrict__ pe_bn_m, const float* __restrict__ pe_bn_v,
    const float* __restrict__ pe_w2, const float* __restrict__ pe_b2,
    const float* __restrict__ bn1g, const float* __restrict__ bn1b,
    const float* __restrict__ bn1m, const float* __restrict__ bn1v,
    const float* __restrict__ at_w1,
    const float* __restrict__ bn2g, const float* __restrict__ bn2b,
    const float* __restrict__ bn2m, const float* __restrict__ bn2v,
    const float* __restrict__ at_w2, const float* __restrict__ at_b2,
    float* __restrict__ y)
{
    const int bb = blockIdx.y;
    const int i0 = blockIdx.x * 4;
    const int t  = threadIdx.x;

    __shared__ float abuf[128][68];
    __shared__ float hbuf[3][64];
    __shared__ int   nidx[64];
    __shared__ float qv[4][128];
    __shared__ float sc1[128], sh1[128], sc2[128], sh2[128];
    __shared__ float pw2t[3][128], pb2s[128], ab2s[128];

    if (t < 128) {
        int c = t;
        float s1 = bn1g[c] / sqrtf(bn1v[c] + BN_EPS);
        sc1[c] = s1; sh1[c] = bn1b[c] - bn1m[c] * s1;
        float s2 = bn2g[c] / sqrtf(bn2v[c] + BN_EPS);
        sc2[c] = s2; sh2[c] = bn2b[c] - bn2m[c] * s2;
        pw2t[0][c] = pe_w2[c * 3 + 0];
        pw2t[1][c] = pe_w2[c * 3 + 1];
        pw2t[2][c] = pe_w2[c * 3 + 2];
        pb2s[c] = pe_b2[c];
        ab2s[c] = at_b2[c];
    } else if (t < 192) {
        int e = t - 128;
        nidx[e] = knn_idx[(bb * NPTS + i0 + (e >> 4)) * 16 + (e & 15)];
    }
    __syncthreads();

    for (int e = t; e < 512; e += 256) {
        int pidx = e >> 7, c = e & 127;
        qv[pidx][c] = qT[(bb * NPTS + i0 + pidx) * NC + c];
    }
    if (t < 64) {
        int pidx = t >> 4;
        int j = nidx[t];
        float pix = p[(bb * NPTS + i0 + pidx) * 3 + 0];
        float piy = p[(bb * NPTS + i0 + pidx) * 3 + 1];
        float piz = p[(bb * NPTS + i0 + pidx) * 3 + 2];
        float rx = p[(bb * NPTS + j) * 3 + 0] - pix;
        float ry = p[(bb * NPTS + j) * 3 + 1] - piy;
        float rz = p[(bb * NPTS + j) * 3 + 2] - piz;
        #pragma unroll
        for (int o = 0; o < 3; o++) {
            float hv = pe_w1[o * 3 + 0] * rx + pe_w1[o * 3 + 1] * ry + pe_w1[o * 3 + 2] * rz;
            float sc = pe_bn_g[o] / sqrtf(pe_bn_v[o] + BN_EPS);
            float sh = pe_bn_b[o] - pe_bn_m[o] * sc;
            hbuf[o][t] = fmaxf(hv * sc + sh, 0.0f);
        }
    }
    __syncthreads();

    for (int e = t; e < 2048; e += 256) {
        int c = e & 127, col4 = e >> 7;
        int pidx = col4 >> 2;
        float qvr = qv[pidx][c];
        float s1 = sc1[c], b1 = sh1[c];
        float pw0 = pw2t[0][c], pw1 = pw2t[1][c], pw2v = pw2t[2][c], pb = pb2s[c];
        float ov[4];
        #pragma unroll
        for (int r = 0; r < 4; r++) {
            int col = col4 * 4 + r;
            int j = nidx[col];
            float gk = kT[(bb * NPTS + j) * NC + c];
            float nrv = pw0 * hbuf[0][col] + pw1 * hbuf[1][col] + pw2v * hbuf[2][col] + pb;
            float a = (qvr - gk + nrv) * s1 + b1;
            ov[r] = fmaxf(a, 0.0f);
        }
        *(float4*)&abuf[c][((col4 ^ ((c >> 3) & 7)) << 2)] =
            make_float4(ov[0], ov[1], ov[2], ov[3]);
    }
    __syncthreads();

    const int pp = t & 3;
    const int c2 = (t >> 2) * 2;
    float acc[2][16];

    #pragma unroll
    for (int a = 0; a < 2; a++)
        #pragma unroll
        for (int kk = 0; kk < 16; kk++) acc[a][kk] = 0.0f;
    for (int cin = 0; cin < 128; cin++) {
        float w0 = at_w1[c2 * NC + cin];
        float w1 = at_w1[(c2 + 1) * NC + cin];
        int g = (cin >> 3) & 7;
        #pragma unroll
        for (int qq = 0; qq < 4; qq++) {
            int col4 = pp * 4 + qq;
            float4 av = *(const float4*)&abuf[cin][((col4 ^ g) << 2)];
            acc[0][qq * 4 + 0] += w0 * av.x; acc[0][qq * 4 + 1] += w0 * av.y;
            acc[0][qq * 4 + 2] += w0 * av.z; acc[0][qq * 4 + 3] += w0 * av.w;
            acc[1][qq * 4 + 0] += w1 * av.x; acc[1][qq * 4 + 1] += w1 * av.y;
            acc[1][qq * 4 + 2] += w1 * av.z; acc[1][qq * 4 + 3] += w1 * av.w;
        }
    }
    __syncthreads();

    #pragma unroll
    for (int a = 0; a < 2; a++) {
        int c = c2 + a;
        float s = sc2[c], bsh = sh2[c];
        int g = (c >> 3) & 7;
        #pragma unroll
        for (int qq = 0; qq < 4; qq++) {
            float v0 = fmaxf(acc[a][qq * 4 + 0] * s + bsh, 0.0f);
            float v1 = fmaxf(acc[a][qq * 4 + 1] * s + bsh, 0.0f);
            float v2 = fmaxf(acc[a][qq * 4 + 2] * s + bsh, 0.0f);
            float v3 = fmaxf(acc[a][qq * 4 + 3] * s + bsh, 0.0f);
            *(float4*)&abuf[c][(((pp * 4 + qq) ^ g) << 2)] = make_float4(v0, v1, v2, v3);
        }
    }
    __syncthreads();

    #pragma unroll
    for (int a = 0; a < 2; a++)
        #pragma unroll
        for (int kk = 0; kk < 16; kk++) acc[a][kk] = 0.0f;
    for (int cin = 0; cin < 128; cin++) {
        float w0 = at_w2[c2 * NC + cin];
        float w1 = at_w2[(c2 + 1) * NC + cin];
        int g = (cin >> 3) & 7;
        #pragma unroll
        for (int qq = 0; qq < 4; qq++) {
            int col4 = pp * 4 + qq;
            float4 av = *(const float4*)&abuf[cin][((col4 ^ g) << 2)];
            acc[0][qq * 4 + 0] += w0 * av.x; acc[0][qq * 4 + 1] += w0 * av.y;
            acc[0][qq * 4 + 2] += w0 * av.z; acc[0][qq * 4 + 3] += w0 * av.w;
            acc[1][qq * 4 + 0] += w1 * av.x; acc[1][qq * 4 + 1] += w1 * av.y;
            acc[1][qq * 4 + 2] += w1 * av.z; acc[1][qq * 4 + 3] += w1 * av.w;
        }
    }

    #pragma unroll
    for (int a = 0; a < 2; a++) {
        int c = c2 + a;
        float bias2 = ab2s[c];
        float m = -3.4e38f;
        #pragma unroll
        for (int kk = 0; kk < 16; kk++) { acc[a][kk] += bias2; m = fmaxf(m, acc[a][kk]); }
        float ex[16];
        float s = 0.0f;
        #pragma unroll
        for (int kk = 0; kk < 16; kk++) { ex[kk] = expf(acc[a][kk] - m); s += ex[kk]; }
        float invs = 1.0f / s;
        float pw0 = pw2t[0][c], pw1 = pw2t[1][c], pw2v = pw2t[2][c], pb = pb2s[c];
        float ysum = 0.0f;
        #pragma unroll
        for (int kk = 0; kk < 16; kk++) {
            int col = pp * 16 + kk;
            int j = nidx[col];
            float gv = vT[(bb * NPTS + j) * NC + c];
            float nrv = pw0 * hbuf[0][col] + pw1 * hbuf[1][col] + pw2v * hbuf[2][col] + pb;
            ysum += (gv + nrv) * (ex[kk] * invs);
        }
        y[(bb * NC + c) * NPTS + i0 + pp] = ysum;
    }
}

// ---------------------------------------------------------------------------
extern "C" void kernel_launch(void* const* d_in, const int* in_sizes, int n_in,
                              void* d_out, int out_size, void* d_ws, size_t ws_size,
                              hipStream_t stream) {
    const float* p     = (const float*)d_in[0];
    const float* x     = (const float*)d_in[1];
    const float* wq    = (const float*)d_in[2];
    const float* bq    = (const float*)d_in[3];
    const float* wk    = (const float*)d_in[4];
    const float* bk    = (const float*)d_in[5];
    const float* wv    = (const float*)d_in[6];
    const float* bv    = (const float*)d_in[7];
    const float* pe_w1 = (const float*)d_in[8];
    const float* pe_bn_g = (const float*)d_in[9];
    const float* pe_bn_b = (const float*)d_in[10];
    const float* pe_bn_m = (const float*)d_in[11];
    const float* pe_bn_v = (const float*)d_in[12];
    const float* pe_w2 = (const float*)d_in[13];
    const float* pe_b2 = (const float*)d_in[14];
    const float* bn1g  = (const float*)d_in[15];
    const float* bn1b  = (const float*)d_in[16];
    const float* bn1m  = (const float*)d_in[17];
    const float* bn1v  = (const float*)d_in[18];
    const float* at_w1 = (const float*)d_in[19];
    const float* bn2g  = (const float*)d_in[20];
    const float* bn2b  = (const float*)d_in[21];
    const float* bn2m  = (const float*)d_in[22];
    const float* bn2v  = (const float*)d_in[23];
    const float* at_w2 = (const float*)d_in[24];
    const float* at_b2 = (const float*)d_in[25];
    float* out = (float*)d_out;

    // workspace layout (25 MB):
    //   [idx 1MB][qT 8MB][kT 8MB][vT 8MB]
    // kNN partial lists (16 MB) alias qT+kT: consumed by knnM BEFORE qkv writes.
    int*   idx  = (int*)d_ws;
    float* qT   = (float*)((char*)d_ws + (1u << 20));
    float* kT   = qT + (size_t)NB * NPTS * NC;
    float* vT   = kT + (size_t)NB * NPTS * NC;
    float2* part = (float2*)qT;

    knnA_kernel<<<dim3(NPTS / 256, NSPLIT, NB), 256, 0, stream>>>(p, part);
    knnM_kernel<<<dim3(NB * NPTS / 256), 256, 0, stream>>>(part, idx);
    qkv_kernel<<<dim3(NPTS / 64, 3, NB), 256, 0, stream>>>(
        x, wq, bq, wk, bk, wv, bv, qT, kT, vT);
    attn_kernel<<<dim3(NPTS / 4, NB), 256, 0, stream>>>(
        p, qT, kT, vT, idx,
        pe_w1, pe_bn_g, pe_bn_b, pe_bn_m, pe_bn_v, pe_w2, pe_b2,
        bn1g, bn1b, bn1m, bn1v, at_w1,
        bn2g, bn2b, bn2m, bn2v, at_w2, at_b2, out);
}

// Round 3
// 566.663 us; speedup vs baseline: 4.6387x; 1.3841x over previous
//
#include <hip/hip_runtime.h>
#include <math.h>

#define NB    2
#define NPTS  8192
#define NC    128
#define NKN   16
#define NSPLIT 16
#define CSPLIT (NPTS / NSPLIT)   // 512
#define BN_EPS 1e-5f

// unconditional sorted-insert of x into ascending d[0..15]:
// nd[0]=min(d0,x); nd[s]=med3(d[s-1],d[s],x). Correct also when x >= d[15].
#define INSERTD(XV)                                                  \
  {                                                                  \
    float x_ = (XV);                                                 \
    float nd_[16];                                                   \
    nd_[0] = fminf(d[0], x_);                                        \
    _Pragma("unroll")                                                \
    for (int s_ = 1; s_ < 16; s_++)                                  \
      nd_[s_] = __builtin_amdgcn_fmed3f(d[s_ - 1], d[s_], x_);       \
    _Pragma("unroll")                                                \
    for (int s_ = 0; s_ < 16; s_++) d[s_] = nd_[s_];                 \
  }

// ---------------------------------------------------------------------------
// Kernel 1: q/k/v = W @ x + b, stored transposed as [b][n][c] for gathers.
// ---------------------------------------------------------------------------
__global__ __launch_bounds__(256) void qkv_kernel(
    const float* __restrict__ x,
    const float* __restrict__ wq, const float* __restrict__ bq,
    const float* __restrict__ wk, const float* __restrict__ bk,
    const float* __restrict__ wv, const float* __restrict__ bv,
    float* __restrict__ qT, float* __restrict__ kT, float* __restrict__ vT)
{
    const int bb  = blockIdx.z;
    const int mat = blockIdx.y;
    const int i0  = blockIdx.x * 64;
    const float* __restrict__ w    = (mat == 0) ? wq : (mat == 1 ? wk : wv);
    const float* __restrict__ bias = (mat == 0) ? bq : (mat == 1 ? bk : bv);
    float* __restrict__ out        = (mat == 0) ? qT : (mat == 1 ? kT : vT);

    __shared__ float xs[128][68];
    for (int e = threadIdx.x; e < 128 * 64; e += 256) {
        int cin = e >> 6, ii = e & 63;
        xs[cin][ii] = x[(bb * NC + cin) * NPTS + i0 + ii];
    }
    __syncthreads();

    const int cbase  = (threadIdx.x & 31) * 4;
    const int iibase = (threadIdx.x >> 5) * 8;
    float acc[4][8];
    #pragma unroll
    for (int a = 0; a < 4; a++)
        #pragma unroll
        for (int b = 0; b < 8; b++) acc[a][b] = 0.0f;

    for (int cin = 0; cin < 128; cin++) {
        float4 xa = *(const float4*)&xs[cin][iibase];
        float4 xb = *(const float4*)&xs[cin][iibase + 4];
        float wr[4];
        #pragma unroll
        for (int a = 0; a < 4; a++) wr[a] = w[(cbase + a) * NC + cin];
        #pragma unroll
        for (int a = 0; a < 4; a++) {
            acc[a][0] += wr[a] * xa.x; acc[a][1] += wr[a] * xa.y;
            acc[a][2] += wr[a] * xa.z; acc[a][3] += wr[a] * xa.w;
            acc[a][4] += wr[a] * xb.x; acc[a][5] += wr[a] * xb.y;
            acc[a][6] += wr[a] * xb.z; acc[a][7] += wr[a] * xb.w;
        }
    }
    #pragma unroll
    for (int a = 0; a < 4; a++) {
        float bb_ = bias[cbase + a];
        #pragma unroll
        for (int b = 0; b < 8; b++)
            out[(bb * NPTS + i0 + iibase + b) * NC + cbase + a] = acc[a][b] + bb_;
    }
}

// ---------------------------------------------------------------------------
// Kernel 2a: kNN phase A — per (query, split) top-16 DISTANCES only.
// Unconditional med3 insertion network: 25 branchless VALU ops / candidate.
// grid (NPTS/256, NSPLIT, NB), block 256.
// ---------------------------------------------------------------------------
__global__ __launch_bounds__(256) void knnA_kernel(
    const float* __restrict__ p,      // [NB][NPTS][3]
    float* __restrict__ partd)        // [NB][NSPLIT][NPTS][16]
{
    const int bb = blockIdx.z, sp = blockIdx.y, q0 = blockIdx.x * 256;
    const int t  = threadIdx.x;

    __shared__ float4 cand[CSPLIT];   // 8 KB
    const float* __restrict__ pc = p + ((size_t)bb * NPTS + sp * CSPLIT) * 3;
    for (int j = t; j < CSPLIT; j += 256) {
        float cx = pc[j * 3 + 0], cy = pc[j * 3 + 1], cz = pc[j * 3 + 2];
        float s  = __fadd_rn(__fadd_rn(__fmul_rn(cx, cx), __fmul_rn(cy, cy)),
                             __fmul_rn(cz, cz));
        cand[j] = make_float4(cx, cy, cz, s);
    }
    __syncthreads();

    const int i = q0 + t;
    const float qx = p[((size_t)bb * NPTS + i) * 3 + 0];
    const float qy = p[((size_t)bb * NPTS + i) * 3 + 1];
    const float qz = p[((size_t)bb * NPTS + i) * 3 + 2];
    const float sqi = __fadd_rn(__fadd_rn(__fmul_rn(qx, qx), __fmul_rn(qy, qy)),
                                __fmul_rn(qz, qz));

    float d[16];
    #pragma unroll
    for (int s = 0; s < 16; s++) d[s] = 3.4e38f;

    #pragma unroll 2
    for (int j = 0; j < CSPLIT; j++) {
        float4 c = cand[j];
        float dot = __fadd_rn(__fadd_rn(__fmul_rn(qx, c.x), __fmul_rn(qy, c.y)),
                              __fmul_rn(qz, c.z));
        float d2 = __fsub_rn(__fadd_rn(sqi, c.w), __fmul_rn(2.0f, dot));
        INSERTD(d2);
    }

    float* __restrict__ row = partd + (((size_t)bb * NSPLIT + sp) * NPTS + i) * 16;
    #pragma unroll
    for (int s = 0; s < 16; s += 4)
        *(float4*)&row[s] = make_float4(d[s], d[s + 1], d[s + 2], d[s + 3]);
}

// ---------------------------------------------------------------------------
// Kernel 2b: merge per-split distance lists -> 16th-smallest threshold.
// grid (NB*NPTS/256), block 256.
// ---------------------------------------------------------------------------
__global__ __launch_bounds__(256) void knnM_kernel(
    const float* __restrict__ partd,
    float* __restrict__ thr)          // [NB*NPTS]
{
    const int gid = blockIdx.x * 256 + threadIdx.x;
    const int bb  = gid >> 13;
    const int i   = gid & (NPTS - 1);

    float d[16];
    const float* __restrict__ r0 = partd + (((size_t)bb * NSPLIT + 0) * NPTS + i) * 16;
    #pragma unroll
    for (int s = 0; s < 16; s += 4) {
        float4 v = *(const float4*)&r0[s];
        d[s] = v.x; d[s + 1] = v.y; d[s + 2] = v.z; d[s + 3] = v.w;
    }
    for (int sp = 1; sp < NSPLIT; sp++) {
        const float* __restrict__ r = partd + (((size_t)bb * NSPLIT + sp) * NPTS + i) * 16;
        #pragma unroll
        for (int s = 0; s < 16; s += 4) {
            float4 v = *(const float4*)&r[s];
            INSERTD(v.x); INSERTD(v.y); INSERTD(v.z); INSERTD(v.w);
        }
    }
    thr[gid] = d[15];
}

// ---------------------------------------------------------------------------
// Kernel 2c: threshold re-scan — append candidate indices with d2 <= thr,
// in ascending index order within each split.
// grid (NPTS/256, NSPLIT, NB), block 256.
// ---------------------------------------------------------------------------
__global__ __launch_bounds__(256) void knnB_kernel(
    const float* __restrict__ p,
    const float* __restrict__ thr,
    int* __restrict__ pidx,           // [NB][NSPLIT][NPTS][16]
    unsigned* __restrict__ pcnt)      // [NB][NSPLIT][NPTS]
{
    const int bb = blockIdx.z, sp = blockIdx.y, q0 = blockIdx.x * 256;
    const int t  = threadIdx.x;

    __shared__ float4 cand[CSPLIT];
    const float* __restrict__ pc = p + ((size_t)bb * NPTS + sp * CSPLIT) * 3;
    for (int j = t; j < CSPLIT; j += 256) {
        float cx = pc[j * 3 + 0], cy = pc[j * 3 + 1], cz = pc[j * 3 + 2];
        float s  = __fadd_rn(__fadd_rn(__fmul_rn(cx, cx), __fmul_rn(cy, cy)),
                             __fmul_rn(cz, cz));
        cand[j] = make_float4(cx, cy, cz, s);
    }
    __syncthreads();

    const int i = q0 + t;
    const float qx = p[((size_t)bb * NPTS + i) * 3 + 0];
    const float qy = p[((size_t)bb * NPTS + i) * 3 + 1];
    const float qz = p[((size_t)bb * NPTS + i) * 3 + 2];
    const float sqi = __fadd_rn(__fadd_rn(__fmul_rn(qx, qx), __fmul_rn(qy, qy)),
                                __fmul_rn(qz, qz));
    const float thv = thr[bb * NPTS + i];

    int cnt = 0;
    int* __restrict__ row = pidx + (((size_t)bb * NSPLIT + sp) * NPTS + i) * 16;
    for (int j = 0; j < CSPLIT; j++) {
        float4 c = cand[j];
        float dot = __fadd_rn(__fadd_rn(__fmul_rn(qx, c.x), __fmul_rn(qy, c.y)),
                              __fmul_rn(qz, c.z));
        float d2 = __fsub_rn(__fadd_rn(sqi, c.w), __fmul_rn(2.0f, dot));
        if (d2 <= thv && cnt < 16) { row[cnt] = sp * CSPLIT + j; cnt++; }
    }
    pcnt[((size_t)bb * NSPLIT + sp) * NPTS + i] = cnt;
}

// ---------------------------------------------------------------------------
// Kernel 2d: finalize — concat per-split appends (ascending index order).
// total==16 fast path; rare tie path does strict-less then equals (matches
// jax.lax.top_k index-stable tie-break).
// grid (NB*NPTS/256), block 256.
// ---------------------------------------------------------------------------
__global__ __launch_bounds__(256) void knnF_kernel(
    const float* __restrict__ p,
    const float* __restrict__ thr,
    const int* __restrict__ pidx,
    const unsigned* __restrict__ pcnt,
    int* __restrict__ knn_idx)        // [NB][NPTS][16]
{
    const int gid = blockIdx.x * 256 + threadIdx.x;
    const int bb  = gid >> 13;
    const int i   = gid & (NPTS - 1);

    int cnts[NSPLIT];
    int total = 0;
    #pragma unroll
    for (int sp = 0; sp < NSPLIT; sp++) {
        cnts[sp] = (int)pcnt[((size_t)bb * NSPLIT + sp) * NPTS + i];
        total += cnts[sp];
    }
    int* __restrict__ out = knn_idx + (size_t)gid * 16;

    if (total == 16) {
        int w = 0;
        for (int sp = 0; sp < NSPLIT; sp++) {
            const int* __restrict__ r = pidx + (((size_t)bb * NSPLIT + sp) * NPTS + i) * 16;
            for (int e = 0; e < cnts[sp]; e++) out[w++] = r[e];
        }
    } else {
        // ties at the threshold (rare): strict-less first, then equals in index order
        const float qx = p[((size_t)bb * NPTS + i) * 3 + 0];
        const float qy = p[((size_t)bb * NPTS + i) * 3 + 1];
        const float qz = p[((size_t)bb * NPTS + i) * 3 + 2];
        const float sqi = __fadd_rn(__fadd_rn(__fmul_rn(qx, qx), __fmul_rn(qy, qy)),
                                    __fmul_rn(qz, qz));
        const float thv = thr[bb * NPTS + i];
        int w = 0;
        for (int pass = 0; pass < 2; pass++) {
            for (int sp = 0; sp < NSPLIT && w < 16; sp++) {
                const int* __restrict__ r = pidx + (((size_t)bb * NSPLIT + sp) * NPTS + i) * 16;
                for (int e = 0; e < cnts[sp] && w < 16; e++) {
                    int j = r[e];
                    float cx = p[((size_t)bb * NPTS + j) * 3 + 0];
                    float cy = p[((size_t)bb * NPTS + j) * 3 + 1];
                    float cz = p[((size_t)bb * NPTS + j) * 3 + 2];
                    float sqj = __fadd_rn(__fadd_rn(__fmul_rn(cx, cx), __fmul_rn(cy, cy)),
                                          __fmul_rn(cz, cz));
                    float dot = __fadd_rn(__fadd_rn(__fmul_rn(qx, cx), __fmul_rn(qy, cy)),
                                          __fmul_rn(qz, cz));
                    float d2 = __fsub_rn(__fadd_rn(sqi, sqj), __fmul_rn(2.0f, dot));
                    bool take = (pass == 0) ? (d2 < thv) : (d2 == thv);
                    if (take) out[w++] = j;
                }
            }
        }
    }
}

// ---------------------------------------------------------------------------
// Kernel 3: fused PE-MLP + attention MLP + softmax + weighted sum.
// (unchanged from round 2)
// ---------------------------------------------------------------------------
__global__ __launch_bounds__(256) void attn_kernel(
    const float* __restrict__ p,
    const float* __restrict__ qT, const float* __restrict__ kT, const float* __restrict__ vT,
    const int*   __restrict__ knn_idx,
    const float* __restrict__ pe_w1,
    const float* __restrict__ pe_bn_g, const float* __restrict__ pe_bn_b,
    const float* __restrict__ pe_bn_m, const float* __restrict__ pe_bn_v,
    const float* __restrict__ pe_w2, const float* __restrict__ pe_b2,
    const float* __restrict__ bn1g, const float* __restrict__ bn1b,
    const float* __restrict__ bn1m, const float* __restrict__ bn1v,
    const float* __restrict__ at_w1,
    const float* __restrict__ bn2g, const float* __restrict__ bn2b,
    const float* __restrict__ bn2m, const float* __restrict__ bn2v,
    const float* __restrict__ at_w2, const float* __restrict__ at_b2,
    float* __restrict__ y)
{
    const int bb = blockIdx.y;
    const int i0 = blockIdx.x * 4;
    const int t  = threadIdx.x;

    __shared__ float abuf[128][68];
    __shared__ float hbuf[3][64];
    __shared__ int   nidx[64];
    __shared__ float qv[4][128];
    __shared__ float sc1[128], sh1[128], sc2[128], sh2[128];
    __shared__ float pw2t[3][128], pb2s[128], ab2s[128];

    if (t < 128) {
        int c = t;
        float s1 = bn1g[c] / sqrtf(bn1v[c] + BN_EPS);
        sc1[c] = s1; sh1[c] = bn1b[c] - bn1m[c] * s1;
        float s2 = bn2g[c] / sqrtf(bn2v[c] + BN_EPS);
        sc2[c] = s2; sh2[c] = bn2b[c] - bn2m[c] * s2;
        pw2t[0][c] = pe_w2[c * 3 + 0];
        pw2t[1][c] = pe_w2[c * 3 + 1];
        pw2t[2][c] = pe_w2[c * 3 + 2];
        pb2s[c] = pe_b2[c];
        ab2s[c] = at_b2[c];
    } else if (t < 192) {
        int e = t - 128;
        nidx[e] = knn_idx[(bb * NPTS + i0 + (e >> 4)) * 16 + (e & 15)];
    }
    __syncthreads();

    for (int e = t; e < 512; e += 256) {
        int pidx_ = e >> 7, c = e & 127;
        qv[pidx_][c] = qT[(bb * NPTS + i0 + pidx_) * NC + c];
    }
    if (t < 64) {
        int pidx_ = t >> 4;
        int j = nidx[t];
        float pix = p[(bb * NPTS + i0 + pidx_) * 3 + 0];
        float piy = p[(bb * NPTS + i0 + pidx_) * 3 + 1];
        float piz = p[(bb * NPTS + i0 + pidx_) * 3 + 2];
        float rx = p[(bb * NPTS + j) * 3 + 0] - pix;
        float ry = p[(bb * NPTS + j) * 3 + 1] - piy;
        float rz = p[(bb * NPTS + j) * 3 + 2] - piz;
        #pragma unroll
        for (int o = 0; o < 3; o++) {
            float hv = pe_w1[o * 3 + 0] * rx + pe_w1[o * 3 + 1] * ry + pe_w1[o * 3 + 2] * rz;
            float sc = pe_bn_g[o] / sqrtf(pe_bn_v[o] + BN_EPS);
            float sh = pe_bn_b[o] - pe_bn_m[o] * sc;
            hbuf[o][t] = fmaxf(hv * sc + sh, 0.0f);
        }
    }
    __syncthreads();

    for (int e = t; e < 2048; e += 256) {
        int c = e & 127, col4 = e >> 7;
        int pidx_ = col4 >> 2;
        float qvr = qv[pidx_][c];
        float s1 = sc1[c], b1 = sh1[c];
        float pw0 = pw2t[0][c], pw1 = pw2t[1][c], pw2v = pw2t[2][c], pb = pb2s[c];
        float ov[4];
        #pragma unroll
        for (int r = 0; r < 4; r++) {
            int col = col4 * 4 + r;
            int j = nidx[col];
            float gk = kT[(bb * NPTS + j) * NC + c];
            float nrv = pw0 * hbuf[0][col] + pw1 * hbuf[1][col] + pw2v * hbuf[2][col] + pb;
            float a = (qvr - gk + nrv) * s1 + b1;
            ov[r] = fmaxf(a, 0.0f);
        }
        *(float4*)&abuf[c][((col4 ^ ((c >> 3) & 7)) << 2)] =
            make_float4(ov[0], ov[1], ov[2], ov[3]);
    }
    __syncthreads();

    const int pp = t & 3;
    const int c2 = (t >> 2) * 2;
    float acc[2][16];

    #pragma unroll
    for (int a = 0; a < 2; a++)
        #pragma unroll
        for (int kk = 0; kk < 16; kk++) acc[a][kk] = 0.0f;
    for (int cin = 0; cin < 128; cin++) {
        float w0 = at_w1[c2 * NC + cin];
        float w1 = at_w1[(c2 + 1) * NC + cin];
        int g = (cin >> 3) & 7;
        #pragma unroll
        for (int qq = 0; qq < 4; qq++) {
            int col4 = pp * 4 + qq;
            float4 av = *(const float4*)&abuf[cin][((col4 ^ g) << 2)];
            acc[0][qq * 4 + 0] += w0 * av.x; acc[0][qq * 4 + 1] += w0 * av.y;
            acc[0][qq * 4 + 2] += w0 * av.z; acc[0][qq * 4 + 3] += w0 * av.w;
            acc[1][qq * 4 + 0] += w1 * av.x; acc[1][qq * 4 + 1] += w1 * av.y;
            acc[1][qq * 4 + 2] += w1 * av.z; acc[1][qq * 4 + 3] += w1 * av.w;
        }
    }
    __syncthreads();

    #pragma unroll
    for (int a = 0; a < 2; a++) {
        int c = c2 + a;
        float s = sc2[c], bsh = sh2[c];
        int g = (c >> 3) & 7;
        #pragma unroll
        for (int qq = 0; qq < 4; qq++) {
            float v0 = fmaxf(acc[a][qq * 4 + 0] * s + bsh, 0.0f);
            float v1 = fmaxf(acc[a][qq * 4 + 1] * s + bsh, 0.0f);
            float v2 = fmaxf(acc[a][qq * 4 + 2] * s + bsh, 0.0f);
            float v3 = fmaxf(acc[a][qq * 4 + 3] * s + bsh, 0.0f);
            *(float4*)&abuf[c][(((pp * 4 + qq) ^ g) << 2)] = make_float4(v0, v1, v2, v3);
        }
    }
    __syncthreads();

    #pragma unroll
    for (int a = 0; a < 2; a++)
        #pragma unroll
        for (int kk = 0; kk < 16; kk++) acc[a][kk] = 0.0f;
    for (int cin = 0; cin < 128; cin++) {
        float w0 = at_w2[c2 * NC + cin];
        float w1 = at_w2[(c2 + 1) * NC + cin];
        int g = (cin >> 3) & 7;
        #pragma unroll
        for (int qq = 0; qq < 4; qq++) {
            int col4 = pp * 4 + qq;
            float4 av = *(const float4*)&abuf[cin][((col4 ^ g) << 2)];
            acc[0][qq * 4 + 0] += w0 * av.x; acc[0][qq * 4 + 1] += w0 * av.y;
            acc[0][qq * 4 + 2] += w0 * av.z; acc[0][qq * 4 + 3] += w0 * av.w;
            acc[1][qq * 4 + 0] += w1 * av.x; acc[1][qq * 4 + 1] += w1 * av.y;
            acc[1][qq * 4 + 2] += w1 * av.z; acc[1][qq * 4 + 3] += w1 * av.w;
        }
    }

    #pragma unroll
    for (int a = 0; a < 2; a++) {
        int c = c2 + a;
        float bias2 = ab2s[c];
        float m = -3.4e38f;
        #pragma unroll
        for (int kk = 0; kk < 16; kk++) { acc[a][kk] += bias2; m = fmaxf(m, acc[a][kk]); }
        float ex[16];
        float s = 0.0f;
        #pragma unroll
        for (int kk = 0; kk < 16; kk++) { ex[kk] = expf(acc[a][kk] - m); s += ex[kk]; }
        float invs = 1.0f / s;
        float pw0 = pw2t[0][c], pw1 = pw2t[1][c], pw2v = pw2t[2][c], pb = pb2s[c];
        float ysum = 0.0f;
        #pragma unroll
        for (int kk = 0; kk < 16; kk++) {
            int col = pp * 16 + kk;
            int j = nidx[col];
            float gv = vT[(bb * NPTS + j) * NC + c];
            float nrv = pw0 * hbuf[0][col] + pw1 * hbuf[1][col] + pw2v * hbuf[2][col] + pb;
            ysum += (gv + nrv) * (ex[kk] * invs);
        }
        y[(bb * NC + c) * NPTS + i0 + pp] = ysum;
    }
}

// ---------------------------------------------------------------------------
extern "C" void kernel_launch(void* const* d_in, const int* in_sizes, int n_in,
                              void* d_out, int out_size, void* d_ws, size_t ws_size,
                              hipStream_t stream) {
    const float* p     = (const float*)d_in[0];
    const float* x     = (const float*)d_in[1];
    const float* wq    = (const float*)d_in[2];
    const float* bq    = (const float*)d_in[3];
    const float* wk    = (const float*)d_in[4];
    const float* bk    = (const float*)d_in[5];
    const float* wv    = (const float*)d_in[6];
    const float* bv    = (const float*)d_in[7];
    const float* pe_w1 = (const float*)d_in[8];
    const float* pe_bn_g = (const float*)d_in[9];
    const float* pe_bn_b = (const float*)d_in[10];
    const float* pe_bn_m = (const float*)d_in[11];
    const float* pe_bn_v = (const float*)d_in[12];
    const float* pe_w2 = (const float*)d_in[13];
    const float* pe_b2 = (const float*)d_in[14];
    const float* bn1g  = (const float*)d_in[15];
    const float* bn1b  = (const float*)d_in[16];
    const float* bn1m  = (const float*)d_in[17];
    const float* bn1v  = (const float*)d_in[18];
    const float* at_w1 = (const float*)d_in[19];
    const float* bn2g  = (const float*)d_in[20];
    const float* bn2b  = (const float*)d_in[21];
    const float* bn2m  = (const float*)d_in[22];
    const float* bn2v  = (const float*)d_in[23];
    const float* at_w2 = (const float*)d_in[24];
    const float* at_b2 = (const float*)d_in[25];
    float* out = (float*)d_out;

    // workspace layout (25 MB total), X = ws + 1MB:
    //   [idx 1MB][ X: qT 8MB | kT 8MB | vT 8MB ]
    // kNN scratch aliases X (all kNN kernels run before qkv writes qT/kT/vT):
    //   partd (16MB) at X         — knnA -> knnM
    //   pidx  (16MB) at X         — knnB -> knnF  (aliases partd, after knnM)
    //   pcnt  ( 2MB) at X + 18MB  — knnB -> knnF
    //   thr   (64KB) at X + 23.5MB— knnM -> knnB/knnF
    char* base = (char*)d_ws;
    int*   idx   = (int*)base;
    char*  X     = base + (1u << 20);
    float* qT    = (float*)X;
    float* kT    = qT + (size_t)NB * NPTS * NC;
    float* vT    = kT + (size_t)NB * NPTS * NC;
    float* partd = (float*)X;
    int*   pidx  = (int*)X;
    unsigned* pcnt = (unsigned*)(X + (size_t)18 * (1u << 20));
    float* thr   = (float*)(X + (size_t)23 * (1u << 20) + (1u << 19));

    knnA_kernel<<<dim3(NPTS / 256, NSPLIT, NB), 256, 0, stream>>>(p, partd);
    knnM_kernel<<<dim3(NB * NPTS / 256), 256, 0, stream>>>(partd, thr);
    knnB_kernel<<<dim3(NPTS / 256, NSPLIT, NB), 256, 0, stream>>>(p, thr, pidx, pcnt);
    knnF_kernel<<<dim3(NB * NPTS / 256), 256, 0, stream>>>(p, thr, pidx, pcnt, idx);
    qkv_kernel<<<dim3(NPTS / 64, 3, NB), 256, 0, stream>>>(
        x, wq, bq, wk, bk, wv, bv, qT, kT, vT);
    attn_kernel<<<dim3(NPTS / 4, NB), 256, 0, stream>>>(
        p, qT, kT, vT, idx,
        pe_w1, pe_bn_g, pe_bn_b, pe_bn_m, pe_bn_v, pe_w2, pe_b2,
        bn1g, bn1b, bn1m, bn1v, at_w1,
        bn2g, bn2b, bn2m, bn2v, at_w2, at_b2, out);
}

// Round 4
// 363.501 us; speedup vs baseline: 7.2313x; 1.5589x over previous
//
#include <hip/hip_runtime.h>
#include <math.h>

#define NB    2
#define NPTS  8192
#define NC    128
#define NKN   16
#define NSPLIT 16
#define CSPLIT (NPTS / NSPLIT)   // 512
#define BN_EPS 1e-5f

typedef short  v8s __attribute__((ext_vector_type(8)));   // 8 bf16 (4 VGPRs)
typedef float  v4f __attribute__((ext_vector_type(4)));

// fp32 -> bf16 with round-to-nearest-even
__device__ __forceinline__ short bf16rne(float f) {
    unsigned u = __float_as_uint(f);
    unsigned r = (u + 0x7FFFu + ((u >> 16) & 1u)) >> 16;
    return (short)r;
}
__device__ __forceinline__ unsigned pack2bf(float a, float b) {
    return (unsigned)(unsigned short)bf16rne(a) | ((unsigned)(unsigned short)bf16rne(b) << 16);
}
__device__ __forceinline__ v8s load_wfrag_bf16(const float* __restrict__ wp) {
    float4 f0 = *(const float4*)wp;
    float4 f1 = *(const float4*)(wp + 4);
    v8s r;
    r[0] = bf16rne(f0.x); r[1] = bf16rne(f0.y); r[2] = bf16rne(f0.z); r[3] = bf16rne(f0.w);
    r[4] = bf16rne(f1.x); r[5] = bf16rne(f1.y); r[6] = bf16rne(f1.z); r[7] = bf16rne(f1.w);
    return r;
}

// unconditional sorted-insert of x into ascending d[0..15]:
// nd[0]=min(d0,x); nd[s]=med3(d[s-1],d[s],x). Correct also when x >= d[15].
#define INSERTD(XV)                                                  \
  {                                                                  \
    float x_ = (XV);                                                 \
    float nd_[16];                                                   \
    nd_[0] = fminf(d[0], x_);                                        \
    _Pragma("unroll")                                                \
    for (int s_ = 1; s_ < 16; s_++)                                  \
      nd_[s_] = __builtin_amdgcn_fmed3f(d[s_ - 1], d[s_], x_);       \
    _Pragma("unroll")                                                \
    for (int s_ = 0; s_ < 16; s_++) d[s_] = nd_[s_];                 \
  }

// ---------------------------------------------------------------------------
// Kernel 1: q/k/v = W @ x + b, stored transposed as [b][n][c] for gathers.
// ---------------------------------------------------------------------------
__global__ __launch_bounds__(256) void qkv_kernel(
    const float* __restrict__ x,
    const float* __restrict__ wq, const float* __restrict__ bq,
    const float* __restrict__ wk, const float* __restrict__ bk,
    const float* __restrict__ wv, const float* __restrict__ bv,
    float* __restrict__ qT, float* __restrict__ kT, float* __restrict__ vT)
{
    const int bb  = blockIdx.z;
    const int mat = blockIdx.y;
    const int i0  = blockIdx.x * 64;
    const float* __restrict__ w    = (mat == 0) ? wq : (mat == 1 ? wk : wv);
    const float* __restrict__ bias = (mat == 0) ? bq : (mat == 1 ? bk : bv);
    float* __restrict__ out        = (mat == 0) ? qT : (mat == 1 ? kT : vT);

    __shared__ __align__(16) float xs[128][68];
    for (int e = threadIdx.x; e < 128 * 64; e += 256) {
        int cin = e >> 6, ii = e & 63;
        xs[cin][ii] = x[(bb * NC + cin) * NPTS + i0 + ii];
    }
    __syncthreads();

    const int cbase  = (threadIdx.x & 31) * 4;
    const int iibase = (threadIdx.x >> 5) * 8;
    float acc[4][8];
    #pragma unroll
    for (int a = 0; a < 4; a++)
        #pragma unroll
        for (int b = 0; b < 8; b++) acc[a][b] = 0.0f;

    for (int cin = 0; cin < 128; cin++) {
        float4 xa = *(const float4*)&xs[cin][iibase];
        float4 xb = *(const float4*)&xs[cin][iibase + 4];
        float wr[4];
        #pragma unroll
        for (int a = 0; a < 4; a++) wr[a] = w[(cbase + a) * NC + cin];
        #pragma unroll
        for (int a = 0; a < 4; a++) {
            acc[a][0] += wr[a] * xa.x; acc[a][1] += wr[a] * xa.y;
            acc[a][2] += wr[a] * xa.z; acc[a][3] += wr[a] * xa.w;
            acc[a][4] += wr[a] * xb.x; acc[a][5] += wr[a] * xb.y;
            acc[a][6] += wr[a] * xb.z; acc[a][7] += wr[a] * xb.w;
        }
    }
    #pragma unroll
    for (int a = 0; a < 4; a++) {
        float bb_ = bias[cbase + a];
        #pragma unroll
        for (int b = 0; b < 8; b++)
            out[(bb * NPTS + i0 + iibase + b) * NC + cbase + a] = acc[a][b] + bb_;
    }
}

// ---------------------------------------------------------------------------
// Kernel 2a: kNN phase A — per (query, split) top-16 DISTANCES only.
// ---------------------------------------------------------------------------
__global__ __launch_bounds__(256) void knnA_kernel(
    const float* __restrict__ p,      // [NB][NPTS][3]
    float* __restrict__ partd)        // [NB][NSPLIT][NPTS][16]
{
    const int bb = blockIdx.z, sp = blockIdx.y, q0 = blockIdx.x * 256;
    const int t  = threadIdx.x;

    __shared__ float4 cand[CSPLIT];   // 8 KB
    const float* __restrict__ pc = p + ((size_t)bb * NPTS + sp * CSPLIT) * 3;
    for (int j = t; j < CSPLIT; j += 256) {
        float cx = pc[j * 3 + 0], cy = pc[j * 3 + 1], cz = pc[j * 3 + 2];
        float s  = __fadd_rn(__fadd_rn(__fmul_rn(cx, cx), __fmul_rn(cy, cy)),
                             __fmul_rn(cz, cz));
        cand[j] = make_float4(cx, cy, cz, s);
    }
    __syncthreads();

    const int i = q0 + t;
    const float qx = p[((size_t)bb * NPTS + i) * 3 + 0];
    const float qy = p[((size_t)bb * NPTS + i) * 3 + 1];
    const float qz = p[((size_t)bb * NPTS + i) * 3 + 2];
    const float sqi = __fadd_rn(__fadd_rn(__fmul_rn(qx, qx), __fmul_rn(qy, qy)),
                                __fmul_rn(qz, qz));

    float d[16];
    #pragma unroll
    for (int s = 0; s < 16; s++) d[s] = 3.4e38f;

    #pragma unroll 2
    for (int j = 0; j < CSPLIT; j++) {
        float4 c = cand[j];
        float dot = __fadd_rn(__fadd_rn(__fmul_rn(qx, c.x), __fmul_rn(qy, c.y)),
                              __fmul_rn(qz, c.z));
        float d2 = __fsub_rn(__fadd_rn(sqi, c.w), __fmul_rn(2.0f, dot));
        INSERTD(d2);
    }

    float* __restrict__ row = partd + (((size_t)bb * NSPLIT + sp) * NPTS + i) * 16;
    #pragma unroll
    for (int s = 0; s < 16; s += 4)
        *(float4*)&row[s] = make_float4(d[s], d[s + 1], d[s + 2], d[s + 3]);
}

// ---------------------------------------------------------------------------
// Kernel 2b: merge per-split distance lists -> 16th-smallest threshold.
// ---------------------------------------------------------------------------
__global__ __launch_bounds__(256) void knnM_kernel(
    const float* __restrict__ partd,
    float* __restrict__ thr)          // [NB*NPTS]
{
    const int gid = blockIdx.x * 256 + threadIdx.x;
    const int bb  = gid >> 13;
    const int i   = gid & (NPTS - 1);

    float d[16];
    const float* __restrict__ r0 = partd + (((size_t)bb * NSPLIT + 0) * NPTS + i) * 16;
    #pragma unroll
    for (int s = 0; s < 16; s += 4) {
        float4 v = *(const float4*)&r0[s];
        d[s] = v.x; d[s + 1] = v.y; d[s + 2] = v.z; d[s + 3] = v.w;
    }
    for (int sp = 1; sp < NSPLIT; sp++) {
        const float* __restrict__ r = partd + (((size_t)bb * NSPLIT + sp) * NPTS + i) * 16;
        #pragma unroll
        for (int s = 0; s < 16; s += 4) {
            float4 v = *(const float4*)&r[s];
            INSERTD(v.x); INSERTD(v.y); INSERTD(v.z); INSERTD(v.w);
        }
    }
    thr[gid] = d[15];
}

// ---------------------------------------------------------------------------
// Kernel 2c: threshold re-scan — append candidate indices with d2 <= thr.
// ---------------------------------------------------------------------------
__global__ __launch_bounds__(256) void knnB_kernel(
    const float* __restrict__ p,
    const float* __restrict__ thr,
    int* __restrict__ pidx,           // [NB][NSPLIT][NPTS][16]
    unsigned* __restrict__ pcnt)      // [NB][NSPLIT][NPTS]
{
    const int bb = blockIdx.z, sp = blockIdx.y, q0 = blockIdx.x * 256;
    const int t  = threadIdx.x;

    __shared__ float4 cand[CSPLIT];
    const float* __restrict__ pc = p + ((size_t)bb * NPTS + sp * CSPLIT) * 3;
    for (int j = t; j < CSPLIT; j += 256) {
        float cx = pc[j * 3 + 0], cy = pc[j * 3 + 1], cz = pc[j * 3 + 2];
        float s  = __fadd_rn(__fadd_rn(__fmul_rn(cx, cx), __fmul_rn(cy, cy)),
                             __fmul_rn(cz, cz));
        cand[j] = make_float4(cx, cy, cz, s);
    }
    __syncthreads();

    const int i = q0 + t;
    const float qx = p[((size_t)bb * NPTS + i) * 3 + 0];
    const float qy = p[((size_t)bb * NPTS + i) * 3 + 1];
    const float qz = p[((size_t)bb * NPTS + i) * 3 + 2];
    const float sqi = __fadd_rn(__fadd_rn(__fmul_rn(qx, qx), __fmul_rn(qy, qy)),
                                __fmul_rn(qz, qz));
    const float thv = thr[bb * NPTS + i];

    int cnt = 0;
    int* __restrict__ row = pidx + (((size_t)bb * NSPLIT + sp) * NPTS + i) * 16;
    for (int j = 0; j < CSPLIT; j++) {
        float4 c = cand[j];
        float dot = __fadd_rn(__fadd_rn(__fmul_rn(qx, c.x), __fmul_rn(qy, c.y)),
                              __fmul_rn(qz, c.z));
        float d2 = __fsub_rn(__fadd_rn(sqi, c.w), __fmul_rn(2.0f, dot));
        if (d2 <= thv && cnt < 16) { row[cnt] = sp * CSPLIT + j; cnt++; }
    }
    pcnt[((size_t)bb * NSPLIT + sp) * NPTS + i] = cnt;
}

// ---------------------------------------------------------------------------
// Kernel 2d: finalize — concat per-split appends (ascending index order).
// ---------------------------------------------------------------------------
__global__ __launch_bounds__(256) void knnF_kernel(
    const float* __restrict__ p,
    const float* __restrict__ thr,
    const int* __restrict__ pidx,
    const unsigned* __restrict__ pcnt,
    int* __restrict__ knn_idx)        // [NB][NPTS][16]
{
    const int gid = blockIdx.x * 256 + threadIdx.x;
    const int bb  = gid >> 13;
    const int i   = gid & (NPTS - 1);

    int cnts[NSPLIT];
    int total = 0;
    #pragma unroll
    for (int sp = 0; sp < NSPLIT; sp++) {
        cnts[sp] = (int)pcnt[((size_t)bb * NSPLIT + sp) * NPTS + i];
        total += cnts[sp];
    }
    int* __restrict__ out = knn_idx + (size_t)gid * 16;

    if (total == 16) {
        int w = 0;
        for (int sp = 0; sp < NSPLIT; sp++) {
            const int* __restrict__ r = pidx + (((size_t)bb * NSPLIT + sp) * NPTS + i) * 16;
            for (int e = 0; e < cnts[sp]; e++) out[w++] = r[e];
        }
    } else {
        const float qx = p[((size_t)bb * NPTS + i) * 3 + 0];
        const float qy = p[((size_t)bb * NPTS + i) * 3 + 1];
        const float qz = p[((size_t)bb * NPTS + i) * 3 + 2];
        const float sqi = __fadd_rn(__fadd_rn(__fmul_rn(qx, qx), __fmul_rn(qy, qy)),
                                    __fmul_rn(qz, qz));
        const float thv = thr[bb * NPTS + i];
        int w = 0;
        for (int pass = 0; pass < 2; pass++) {
            for (int sp = 0; sp < NSPLIT && w < 16; sp++) {
                const int* __restrict__ r = pidx + (((size_t)bb * NSPLIT + sp) * NPTS + i) * 16;
                for (int e = 0; e < cnts[sp] && w < 16; e++) {
                    int j = r[e];
                    float cx = p[((size_t)bb * NPTS + j) * 3 + 0];
                    float cy = p[((size_t)bb * NPTS + j) * 3 + 1];
                    float cz = p[((size_t)bb * NPTS + j) * 3 + 2];
                    float sqj = __fadd_rn(__fadd_rn(__fmul_rn(cx, cx), __fmul_rn(cy, cy)),
                                          __fmul_rn(cz, cz));
                    float dot = __fadd_rn(__fadd_rn(__fmul_rn(qx, cx), __fmul_rn(qy, cy)),
                                          __fmul_rn(qz, cz));
                    float d2 = __fsub_rn(__fadd_rn(sqi, sqj), __fmul_rn(2.0f, dot));
                    bool take = (pass == 0) ? (d2 < thv) : (d2 == thv);
                    if (take) out[w++] = j;
                }
            }
        }
    }
}

// ---------------------------------------------------------------------------
// Kernel 3: fused PE-MLP + attention MLP (bf16 MFMA) + softmax + weighted sum.
// 8 points/block -> 128 cols (col = point*16 + neighbor). 4 waves; wave w owns
// output channels [w*32, w*32+32) as 2 row-tiles; 8 col-tiles; K=128 in 4 MFMA
// steps of v_mfma_f32_16x16x32_bf16. a1/a2 share one bf16 LDS buffer [col][k]
// with XOR swizzle (k ^ ((col&7)<<3)) in ushort units -> <=2-way banks.
// One 16-col tile = all 16 neighbors of one point -> softmax over k is a
// 16-lane shfl_xor butterfly on the accumulator layout (col=lane&15,
// row=(lane>>4)*4+reg). Normalization folded into the butterfly.
// grid (NPTS/8, NB), block 256
// ---------------------------------------------------------------------------
__global__ __launch_bounds__(256) void attn_kernel(
    const float* __restrict__ p,
    const float* __restrict__ qT, const float* __restrict__ kT, const float* __restrict__ vT,
    const int*   __restrict__ knn_idx,
    const float* __restrict__ pe_w1,
    const float* __restrict__ pe_bn_g, const float* __restrict__ pe_bn_b,
    const float* __restrict__ pe_bn_m, const float* __restrict__ pe_bn_v,
    const float* __restrict__ pe_w2, const float* __restrict__ pe_b2,
    const float* __restrict__ bn1g, const float* __restrict__ bn1b,
    const float* __restrict__ bn1m, const float* __restrict__ bn1v,
    const float* __restrict__ at_w1,
    const float* __restrict__ bn2g, const float* __restrict__ bn2b,
    const float* __restrict__ bn2m, const float* __restrict__ bn2v,
    const float* __restrict__ at_w2, const float* __restrict__ at_b2,
    float* __restrict__ y)
{
    const int bb = blockIdx.y;
    const int i0 = blockIdx.x * 8;
    const int t  = threadIdx.x;
    const int w  = t >> 6;          // wave 0..3
    const int l  = t & 63;          // lane
    const int lm = t & 15;          // lane&15
    const int lq = l >> 4;          // quarter-wave 0..3

    __shared__ __align__(16) unsigned short a1s[128 * 128];   // 32 KB bf16 [col][k^swz]
    __shared__ __align__(16) float hbuf[3][128];
    __shared__ __align__(16) int   nidx[128];
    __shared__ __align__(16) float sc1[128], sh1[128], sc2[128], sh2[128];
    __shared__ __align__(16) float pw2t[3][128], pb2s[128], ab2s[128];

    // ---- phase 0: params + neighbor indices ----
    if (t < 128) {
        int c = t;
        float s1 = bn1g[c] / sqrtf(bn1v[c] + BN_EPS);
        sc1[c] = s1; sh1[c] = bn1b[c] - bn1m[c] * s1;
        float s2 = bn2g[c] / sqrtf(bn2v[c] + BN_EPS);
        sc2[c] = s2; sh2[c] = bn2b[c] - bn2m[c] * s2;
        pw2t[0][c] = pe_w2[c * 3 + 0];
        pw2t[1][c] = pe_w2[c * 3 + 1];
        pw2t[2][c] = pe_w2[c * 3 + 2];
        pb2s[c] = pe_b2[c];
        ab2s[c] = at_b2[c];
    } else {
        int e = t - 128;
        nidx[e] = knn_idx[(bb * NPTS + i0 + (e >> 4)) * 16 + (e & 15)];
    }
    __syncthreads();

    // ---- phase 0b: positional-encoding hidden layer (fp32) ----
    if (t < 128) {
        int pt = t >> 4;
        int j = nidx[t];
        float pix = p[((size_t)bb * NPTS + i0 + pt) * 3 + 0];
        float piy = p[((size_t)bb * NPTS + i0 + pt) * 3 + 1];
        float piz = p[((size_t)bb * NPTS + i0 + pt) * 3 + 2];
        float rx = p[((size_t)bb * NPTS + j) * 3 + 0] - pix;
        float ry = p[((size_t)bb * NPTS + j) * 3 + 1] - piy;
        float rz = p[((size_t)bb * NPTS + j) * 3 + 2] - piz;
        #pragma unroll
        for (int o = 0; o < 3; o++) {
            float hv = pe_w1[o * 3 + 0] * rx + pe_w1[o * 3 + 1] * ry + pe_w1[o * 3 + 2] * rz;
            float sc = pe_bn_g[o] / sqrtf(pe_bn_v[o] + BN_EPS);
            float sh = pe_bn_b[o] - pe_bn_m[o] * sc;
            hbuf[o][t] = fmaxf(hv * sc + sh, 0.0f);
        }
    }
    __syncthreads();

    // ---- phase 1: a1 = relu(bn1(q - gk + n_r)) -> bf16 LDS (swizzled) ----
    {
        const int c0 = 2 * l, c1 = 2 * l + 1;
        const float s1a = sc1[c0], b1a = sh1[c0], s1b = sc1[c1], b1b = sh1[c1];
        const float pwa0 = pw2t[0][c0], pwa1 = pw2t[1][c0], pwa2 = pw2t[2][c0], pba = pb2s[c0];
        const float pwb0 = pw2t[0][c1], pwb1 = pw2t[1][c1], pwb2 = pw2t[2][c1], pbb = pb2s[c1];
        unsigned* a1u = (unsigned*)a1s;
        for (int it = 0; it < 32; ++it) {
            int col = w + 4 * it;
            int pt  = col >> 4;
            int j   = nidx[col];
            float2 qv2 = *(const float2*)&qT[((size_t)(bb * NPTS + i0 + pt)) * NC + c0];
            float2 kv2 = *(const float2*)&kT[((size_t)(bb * NPTS + j)) * NC + c0];
            float h0 = hbuf[0][col], h1 = hbuf[1][col], h2 = hbuf[2][col];
            float nra = pwa0 * h0 + pwa1 * h1 + pwa2 * h2 + pba;
            float nrb = pwb0 * h0 + pwb1 * h1 + pwb2 * h2 + pbb;
            float a0 = fmaxf((qv2.x - kv2.x + nra) * s1a + b1a, 0.0f);
            float a1v = fmaxf((qv2.y - kv2.y + nrb) * s1b + b1b, 0.0f);
            a1u[col * 64 + (l ^ ((col & 7) << 2))] = pack2bf(a0, a1v);
        }
    }

    // ---- W1 fragments (fp32->bf16 in regs; L2-resident, all blocks share) ----
    v8s wf[2][4];
    #pragma unroll
    for (int rt = 0; rt < 2; rt++)
        #pragma unroll
        for (int ks = 0; ks < 4; ks++)
            wf[rt][ks] = load_wfrag_bf16(at_w1 + (size_t)(w * 32 + rt * 16 + lm) * NC + ks * 32 + lq * 8);

    __syncthreads();

    // ---- GEMM1: a2 = at_w1 @ a1 (MFMA) ----
    v4f acc[2][8];
    #pragma unroll
    for (int rt = 0; rt < 2; rt++)
        #pragma unroll
        for (int ct = 0; ct < 8; ct++) acc[rt][ct] = (v4f)0.0f;

    #pragma unroll
    for (int ct = 0; ct < 8; ct++) {
        const int col = ct * 16 + lm;
        const int sw8 = (col & 7) << 3;
        #pragma unroll
        for (int ks = 0; ks < 4; ks++) {
            v8s b = *(const v8s*)&a1s[col * 128 + ((ks * 32 + lq * 8) ^ sw8)];
            acc[0][ct] = __builtin_amdgcn_mfma_f32_16x16x32_bf16(wf[0][ks], b, acc[0][ct], 0, 0, 0);
            acc[1][ct] = __builtin_amdgcn_mfma_f32_16x16x32_bf16(wf[1][ks], b, acc[1][ct], 0, 0, 0);
        }
    }
    __syncthreads();   // all GEMM1 reads done before overwrite

    // ---- bn2 + relu -> bf16 back into same LDS buffer ----
    #pragma unroll
    for (int rt = 0; rt < 2; rt++) {
        const int r0 = w * 32 + rt * 16 + lq * 4;
        float4 scv = *(const float4*)&sc2[r0];
        float4 shv = *(const float4*)&sh2[r0];
        #pragma unroll
        for (int ct = 0; ct < 8; ct++) {
            const int col = ct * 16 + lm;
            v4f v = acc[rt][ct];
            float x0 = fmaxf(v[0] * scv.x + shv.x, 0.0f);
            float x1 = fmaxf(v[1] * scv.y + shv.y, 0.0f);
            float x2 = fmaxf(v[2] * scv.z + shv.z, 0.0f);
            float x3 = fmaxf(v[3] * scv.w + shv.w, 0.0f);
            *(uint2*)&a1s[col * 128 + (r0 ^ ((col & 7) << 3))] =
                make_uint2(pack2bf(x0, x1), pack2bf(x2, x3));
        }
    }

    // ---- W2 fragments ----
    #pragma unroll
    for (int rt = 0; rt < 2; rt++)
        #pragma unroll
        for (int ks = 0; ks < 4; ks++)
            wf[rt][ks] = load_wfrag_bf16(at_w2 + (size_t)(w * 32 + rt * 16 + lm) * NC + ks * 32 + lq * 8);

    __syncthreads();

    // ---- GEMM2: logits = at_w2 @ a2 (MFMA) ----
    #pragma unroll
    for (int rt = 0; rt < 2; rt++)
        #pragma unroll
        for (int ct = 0; ct < 8; ct++) acc[rt][ct] = (v4f)0.0f;

    #pragma unroll
    for (int ct = 0; ct < 8; ct++) {
        const int col = ct * 16 + lm;
        const int sw8 = (col & 7) << 3;
        #pragma unroll
        for (int ks = 0; ks < 4; ks++) {
            v8s b = *(const v8s*)&a1s[col * 128 + ((ks * 32 + lq * 8) ^ sw8)];
            acc[0][ct] = __builtin_amdgcn_mfma_f32_16x16x32_bf16(wf[0][ks], b, acc[0][ct], 0, 0, 0);
            acc[1][ct] = __builtin_amdgcn_mfma_f32_16x16x32_bf16(wf[1][ks], b, acc[1][ct], 0, 0, 0);
        }
    }

    // ---- bias + softmax over neighbors (16-lane butterfly) + weighted sum ----
    // logits bounded ~|1.5|: skip max-subtraction; fold normalization into the
    // reduction (sum ex and sum (v+nr)*ex together, one divide at the end).
    #pragma unroll
    for (int ct = 0; ct < 8; ct++) {
        const int col = ct * 16 + lm;          // neighbor nb = lm
        const int j   = nidx[col];
        const float h0 = hbuf[0][col], h1 = hbuf[1][col], h2 = hbuf[2][col];
        #pragma unroll
        for (int rt = 0; rt < 2; rt++) {
            const int r0 = w * 32 + rt * 16 + lq * 4;
            float4 b4  = *(const float4*)&ab2s[r0];
            float4 p0  = *(const float4*)&pw2t[0][r0];
            float4 p1  = *(const float4*)&pw2t[1][r0];
            float4 p2  = *(const float4*)&pw2t[2][r0];
            float4 pbv = *(const float4*)&pb2s[r0];
            float4 vv  = *(const float4*)&vT[((size_t)(bb * NPTS + j)) * NC + r0];
            v4f lg = acc[rt][ct];
            float ex[4], pr[4];
            {
                float e0 = __expf(lg[0] + b4.x);
                float e1 = __expf(lg[1] + b4.y);
                float e2 = __expf(lg[2] + b4.z);
                float e3 = __expf(lg[3] + b4.w);
                float n0 = p0.x * h0 + p1.x * h1 + p2.x * h2 + pbv.x;
                float n1 = p0.y * h0 + p1.y * h1 + p2.y * h2 + pbv.y;
                float n2 = p0.z * h0 + p1.z * h1 + p2.z * h2 + pbv.z;
                float n3 = p0.w * h0 + p1.w * h1 + p2.w * h2 + pbv.w;
                ex[0] = e0; pr[0] = (vv.x + n0) * e0;
                ex[1] = e1; pr[1] = (vv.y + n1) * e1;
                ex[2] = e2; pr[2] = (vv.z + n2) * e2;
                ex[3] = e3; pr[3] = (vv.w + n3) * e3;
            }
            #pragma unroll
            for (int dlt = 1; dlt < 16; dlt <<= 1) {
                #pragma unroll
                for (int m = 0; m < 4; m++) {
                    ex[m] += __shfl_xor(ex[m], dlt);
                    pr[m] += __shfl_xor(pr[m], dlt);
                }
            }
            #pragma unroll
            for (int m = 0; m < 4; m++)
                if (lm == m)
                    y[((size_t)bb * NC + r0 + m) * NPTS + i0 + ct] = pr[m] / ex[m];
        }
    }
}

// ---------------------------------------------------------------------------
extern "C" void kernel_launch(void* const* d_in, const int* in_sizes, int n_in,
                              void* d_out, int out_size, void* d_ws, size_t ws_size,
                              hipStream_t stream) {
    const float* p     = (const float*)d_in[0];
    const float* x     = (const float*)d_in[1];
    const float* wq    = (const float*)d_in[2];
    const float* bq    = (const float*)d_in[3];
    const float* wk    = (const float*)d_in[4];
    const float* bk    = (const float*)d_in[5];
    const float* wv    = (const float*)d_in[6];
    const float* bv    = (const float*)d_in[7];
    const float* pe_w1 = (const float*)d_in[8];
    const float* pe_bn_g = (const float*)d_in[9];
    const float* pe_bn_b = (const float*)d_in[10];
    const float* pe_bn_m = (const float*)d_in[11];
    const float* pe_bn_v = (const float*)d_in[12];
    const float* pe_w2 = (const float*)d_in[13];
    const float* pe_b2 = (const float*)d_in[14];
    const float* bn1g  = (const float*)d_in[15];
    const float* bn1b  = (const float*)d_in[16];
    const float* bn1m  = (const float*)d_in[17];
    const float* bn1v  = (const float*)d_in[18];
    const float* at_w1 = (const float*)d_in[19];
    const float* bn2g  = (const float*)d_in[20];
    const float* bn2b  = (const float*)d_in[21];
    const float* bn2m  = (const float*)d_in[22];
    const float* bn2v  = (const float*)d_in[23];
    const float* at_w2 = (const float*)d_in[24];
    const float* at_b2 = (const float*)d_in[25];
    float* out = (float*)d_out;

    // workspace layout (25 MB total), X = ws + 1MB:
    //   [idx 1MB][ X: qT 8MB | kT 8MB | vT 8MB ]
    // kNN scratch aliases X (all kNN kernels run before qkv writes qT/kT/vT).
    char* base = (char*)d_ws;
    int*   idx   = (int*)base;
    char*  X     = base + (1u << 20);
    float* qT    = (float*)X;
    float* kT    = qT + (size_t)NB * NPTS * NC;
    float* vT    = kT + (size_t)NB * NPTS * NC;
    float* partd = (float*)X;
    int*   pidx  = (int*)X;
    unsigned* pcnt = (unsigned*)(X + (size_t)18 * (1u << 20));
    float* thr   = (float*)(X + (size_t)23 * (1u << 20) + (1u << 19));

    knnA_kernel<<<dim3(NPTS / 256, NSPLIT, NB), 256, 0, stream>>>(p, partd);
    knnM_kernel<<<dim3(NB * NPTS / 256), 256, 0, stream>>>(partd, thr);
    knnB_kernel<<<dim3(NPTS / 256, NSPLIT, NB), 256, 0, stream>>>(p, thr, pidx, pcnt);
    knnF_kernel<<<dim3(NB * NPTS / 256), 256, 0, stream>>>(p, thr, pidx, pcnt, idx);
    qkv_kernel<<<dim3(NPTS / 64, 3, NB), 256, 0, stream>>>(
        x, wq, bq, wk, bk, wv, bv, qT, kT, vT);
    attn_kernel<<<dim3(NPTS / 8, NB), 256, 0, stream>>>(
        p, qT, kT, vT, idx,
        pe_w1, pe_bn_g, pe_bn_b, pe_bn_m, pe_bn_v, pe_w2, pe_b2,
        bn1g, bn1b, bn1m, bn1v, at_w1,
        bn2g, bn2b, bn2m, bn2v, at_w2, at_b2, out);
}

// Round 5
// 338.687 us; speedup vs baseline: 7.7611x; 1.0733x over previous
//
#include <hip/hip_runtime.h>
#include <math.h>

#define NB    2
#define NPTS  8192
#define NC    128
#define NKN   16
#define NSPLIT 16
#define CSPLIT (NPTS / NSPLIT)   // 512
#define BN_EPS 1e-5f

typedef short  v8s __attribute__((ext_vector_type(8)));   // 8 bf16 (4 VGPRs)
typedef float  v4f __attribute__((ext_vector_type(4)));

// fp32 -> bf16 with round-to-nearest-even
__device__ __forceinline__ short bf16rne(float f) {
    unsigned u = __float_as_uint(f);
    unsigned r = (u + 0x7FFFu + ((u >> 16) & 1u)) >> 16;
    return (short)r;
}
__device__ __forceinline__ unsigned pack2bf(float a, float b) {
    return (unsigned)(unsigned short)bf16rne(a) | ((unsigned)(unsigned short)bf16rne(b) << 16);
}
__device__ __forceinline__ v8s load_wfrag_bf16(const float* __restrict__ wp) {
    float4 f0 = *(const float4*)wp;
    float4 f1 = *(const float4*)(wp + 4);
    v8s r;
    r[0] = bf16rne(f0.x); r[1] = bf16rne(f0.y); r[2] = bf16rne(f0.z); r[3] = bf16rne(f0.w);
    r[4] = bf16rne(f1.x); r[5] = bf16rne(f1.y); r[6] = bf16rne(f1.z); r[7] = bf16rne(f1.w);
    return r;
}

// unconditional sorted-insert of x into ascending d[0..15]:
// nd[0]=min(d0,x); nd[s]=med3(d[s-1],d[s],x). Correct also when x >= d[15].
#define INSERTD(XV)                                                  \
  {                                                                  \
    float x_ = (XV);                                                 \
    float nd_[16];                                                   \
    nd_[0] = fminf(d[0], x_);                                        \
    _Pragma("unroll")                                                \
    for (int s_ = 1; s_ < 16; s_++)                                  \
      nd_[s_] = __builtin_amdgcn_fmed3f(d[s_ - 1], d[s_], x_);       \
    _Pragma("unroll")                                                \
    for (int s_ = 0; s_ < 16; s_++) d[s_] = nd_[s_];                 \
  }

// ---------------------------------------------------------------------------
// Kernel 1: q/k/v = W @ x + b, stored transposed as [b][n][c] for gathers.
// ---------------------------------------------------------------------------
__global__ __launch_bounds__(256) void qkv_kernel(
    const float* __restrict__ x,
    const float* __restrict__ wq, const float* __restrict__ bq,
    const float* __restrict__ wk, const float* __restrict__ bk,
    const float* __restrict__ wv, const float* __restrict__ bv,
    float* __restrict__ qT, float* __restrict__ kT, float* __restrict__ vT)
{
    const int bb  = blockIdx.z;
    const int mat = blockIdx.y;
    const int i0  = blockIdx.x * 64;
    const float* __restrict__ w    = (mat == 0) ? wq : (mat == 1 ? wk : wv);
    const float* __restrict__ bias = (mat == 0) ? bq : (mat == 1 ? bk : bv);
    float* __restrict__ out        = (mat == 0) ? qT : (mat == 1 ? kT : vT);

    __shared__ __align__(16) float xs[128][68];
    for (int e = threadIdx.x; e < 128 * 64; e += 256) {
        int cin = e >> 6, ii = e & 63;
        xs[cin][ii] = x[(bb * NC + cin) * NPTS + i0 + ii];
    }
    __syncthreads();

    const int cbase  = (threadIdx.x & 31) * 4;
    const int iibase = (threadIdx.x >> 5) * 8;
    float acc[4][8];
    #pragma unroll
    for (int a = 0; a < 4; a++)
        #pragma unroll
        for (int b = 0; b < 8; b++) acc[a][b] = 0.0f;

    for (int cin = 0; cin < 128; cin++) {
        float4 xa = *(const float4*)&xs[cin][iibase];
        float4 xb = *(const float4*)&xs[cin][iibase + 4];
        float wr[4];
        #pragma unroll
        for (int a = 0; a < 4; a++) wr[a] = w[(cbase + a) * NC + cin];
        #pragma unroll
        for (int a = 0; a < 4; a++) {
            acc[a][0] += wr[a] * xa.x; acc[a][1] += wr[a] * xa.y;
            acc[a][2] += wr[a] * xa.z; acc[a][3] += wr[a] * xa.w;
            acc[a][4] += wr[a] * xb.x; acc[a][5] += wr[a] * xb.y;
            acc[a][6] += wr[a] * xb.z; acc[a][7] += wr[a] * xb.w;
        }
    }
    #pragma unroll
    for (int a = 0; a < 4; a++) {
        float bb_ = bias[cbase + a];
        #pragma unroll
        for (int b = 0; b < 8; b++)
            out[(bb * NPTS + i0 + iibase + b) * NC + cbase + a] = acc[a][b] + bb_;
    }
}

// ---------------------------------------------------------------------------
// Kernel 2a: kNN phase A — per (query, split) top-16 DISTANCES only.
// ---------------------------------------------------------------------------
__global__ __launch_bounds__(256) void knnA_kernel(
    const float* __restrict__ p,      // [NB][NPTS][3]
    float* __restrict__ partd)        // [NB][NSPLIT][NPTS][16]
{
    const int bb = blockIdx.z, sp = blockIdx.y, q0 = blockIdx.x * 256;
    const int t  = threadIdx.x;

    __shared__ float4 cand[CSPLIT];   // 8 KB
    const float* __restrict__ pc = p + ((size_t)bb * NPTS + sp * CSPLIT) * 3;
    for (int j = t; j < CSPLIT; j += 256) {
        float cx = pc[j * 3 + 0], cy = pc[j * 3 + 1], cz = pc[j * 3 + 2];
        float s  = __fadd_rn(__fadd_rn(__fmul_rn(cx, cx), __fmul_rn(cy, cy)),
                             __fmul_rn(cz, cz));
        cand[j] = make_float4(cx, cy, cz, s);
    }
    __syncthreads();

    const int i = q0 + t;
    const float qx = p[((size_t)bb * NPTS + i) * 3 + 0];
    const float qy = p[((size_t)bb * NPTS + i) * 3 + 1];
    const float qz = p[((size_t)bb * NPTS + i) * 3 + 2];
    const float sqi = __fadd_rn(__fadd_rn(__fmul_rn(qx, qx), __fmul_rn(qy, qy)),
                                __fmul_rn(qz, qz));

    float d[16];
    #pragma unroll
    for (int s = 0; s < 16; s++) d[s] = 3.4e38f;

    #pragma unroll 2
    for (int j = 0; j < CSPLIT; j++) {
        float4 c = cand[j];
        float dot = __fadd_rn(__fadd_rn(__fmul_rn(qx, c.x), __fmul_rn(qy, c.y)),
                              __fmul_rn(qz, c.z));
        float d2 = __fsub_rn(__fadd_rn(sqi, c.w), __fmul_rn(2.0f, dot));
        INSERTD(d2);
    }

    float* __restrict__ row = partd + (((size_t)bb * NSPLIT + sp) * NPTS + i) * 16;
    #pragma unroll
    for (int s = 0; s < 16; s += 4)
        *(float4*)&row[s] = make_float4(d[s], d[s + 1], d[s + 2], d[s + 3]);
}

// ---------------------------------------------------------------------------
// Kernel 2b: merge per-split distance lists -> 16th-smallest threshold.
// ---------------------------------------------------------------------------
__global__ __launch_bounds__(256) void knnM_kernel(
    const float* __restrict__ partd,
    float* __restrict__ thr)          // [NB*NPTS]
{
    const int gid = blockIdx.x * 256 + threadIdx.x;
    const int bb  = gid >> 13;
    const int i   = gid & (NPTS - 1);

    float d[16];
    const float* __restrict__ r0 = partd + (((size_t)bb * NSPLIT + 0) * NPTS + i) * 16;
    #pragma unroll
    for (int s = 0; s < 16; s += 4) {
        float4 v = *(const float4*)&r0[s];
        d[s] = v.x; d[s + 1] = v.y; d[s + 2] = v.z; d[s + 3] = v.w;
    }
    for (int sp = 1; sp < NSPLIT; sp++) {
        const float* __restrict__ r = partd + (((size_t)bb * NSPLIT + sp) * NPTS + i) * 16;
        #pragma unroll
        for (int s = 0; s < 16; s += 4) {
            float4 v = *(const float4*)&r[s];
            INSERTD(v.x); INSERTD(v.y); INSERTD(v.z); INSERTD(v.w);
        }
    }
    thr[gid] = d[15];
}

// ---------------------------------------------------------------------------
// Kernel 2c: threshold re-scan — append candidate indices with d2 <= thr.
// ---------------------------------------------------------------------------
__global__ __launch_bounds__(256) void knnB_kernel(
    const float* __restrict__ p,
    const float* __restrict__ thr,
    int* __restrict__ pidx,           // [NB][NSPLIT][NPTS][16]
    unsigned* __restrict__ pcnt)      // [NB][NSPLIT][NPTS]
{
    const int bb = blockIdx.z, sp = blockIdx.y, q0 = blockIdx.x * 256;
    const int t  = threadIdx.x;

    __shared__ float4 cand[CSPLIT];
    const float* __restrict__ pc = p + ((size_t)bb * NPTS + sp * CSPLIT) * 3;
    for (int j = t; j < CSPLIT; j += 256) {
        float cx = pc[j * 3 + 0], cy = pc[j * 3 + 1], cz = pc[j * 3 + 2];
        float s  = __fadd_rn(__fadd_rn(__fmul_rn(cx, cx), __fmul_rn(cy, cy)),
                             __fmul_rn(cz, cz));
        cand[j] = make_float4(cx, cy, cz, s);
    }
    __syncthreads();

    const int i = q0 + t;
    const float qx = p[((size_t)bb * NPTS + i) * 3 + 0];
    const float qy = p[((size_t)bb * NPTS + i) * 3 + 1];
    const float qz = p[((size_t)bb * NPTS + i) * 3 + 2];
    const float sqi = __fadd_rn(__fadd_rn(__fmul_rn(qx, qx), __fmul_rn(qy, qy)),
                                __fmul_rn(qz, qz));
    const float thv = thr[bb * NPTS + i];

    int cnt = 0;
    int* __restrict__ row = pidx + (((size_t)bb * NSPLIT + sp) * NPTS + i) * 16;
    for (int j = 0; j < CSPLIT; j++) {
        float4 c = cand[j];
        float dot = __fadd_rn(__fadd_rn(__fmul_rn(qx, c.x), __fmul_rn(qy, c.y)),
                              __fmul_rn(qz, c.z));
        float d2 = __fsub_rn(__fadd_rn(sqi, c.w), __fmul_rn(2.0f, dot));
        if (d2 <= thv && cnt < 16) { row[cnt] = sp * CSPLIT + j; cnt++; }
    }
    pcnt[((size_t)bb * NSPLIT + sp) * NPTS + i] = cnt;
}

// ---------------------------------------------------------------------------
// Kernel 2d: finalize — concat per-split appends (ascending index order).
// ---------------------------------------------------------------------------
__global__ __launch_bounds__(256) void knnF_kernel(
    const float* __restrict__ p,
    const float* __restrict__ thr,
    const int* __restrict__ pidx,
    const unsigned* __restrict__ pcnt,
    int* __restrict__ knn_idx)        // [NB][NPTS][16]
{
    const int gid = blockIdx.x * 256 + threadIdx.x;
    const int bb  = gid >> 13;
    const int i   = gid & (NPTS - 1);

    int cnts[NSPLIT];
    int total = 0;
    #pragma unroll
    for (int sp = 0; sp < NSPLIT; sp++) {
        cnts[sp] = (int)pcnt[((size_t)bb * NSPLIT + sp) * NPTS + i];
        total += cnts[sp];
    }
    int* __restrict__ out = knn_idx + (size_t)gid * 16;

    if (total == 16) {
        int w = 0;
        for (int sp = 0; sp < NSPLIT; sp++) {
            const int* __restrict__ r = pidx + (((size_t)bb * NSPLIT + sp) * NPTS + i) * 16;
            for (int e = 0; e < cnts[sp]; e++) out[w++] = r[e];
        }
    } else {
        const float qx = p[((size_t)bb * NPTS + i) * 3 + 0];
        const float qy = p[((size_t)bb * NPTS + i) * 3 + 1];
        const float qz = p[((size_t)bb * NPTS + i) * 3 + 2];
        const float sqi = __fadd_rn(__fadd_rn(__fmul_rn(qx, qx), __fmul_rn(qy, qy)),
                                    __fmul_rn(qz, qz));
        const float thv = thr[bb * NPTS + i];
        int w = 0;
        for (int pass = 0; pass < 2; pass++) {
            for (int sp = 0; sp < NSPLIT && w < 16; sp++) {
                const int* __restrict__ r = pidx + (((size_t)bb * NSPLIT + sp) * NPTS + i) * 16;
                for (int e = 0; e < cnts[sp] && w < 16; e++) {
                    int j = r[e];
                    float cx = p[((size_t)bb * NPTS + j) * 3 + 0];
                    float cy = p[((size_t)bb * NPTS + j) * 3 + 1];
                    float cz = p[((size_t)bb * NPTS + j) * 3 + 2];
                    float sqj = __fadd_rn(__fadd_rn(__fmul_rn(cx, cx), __fmul_rn(cy, cy)),
                                          __fmul_rn(cz, cz));
                    float dot = __fadd_rn(__fadd_rn(__fmul_rn(qx, cx), __fmul_rn(qy, cy)),
                                          __fmul_rn(qz, cz));
                    float d2 = __fsub_rn(__fadd_rn(sqi, sqj), __fmul_rn(2.0f, dot));
                    bool take = (pass == 0) ? (d2 < thv) : (d2 == thv);
                    if (take) out[w++] = j;
                }
            }
        }
    }
}

// ---------------------------------------------------------------------------
// Kernel 3: fused PE-MLP + attention MLP (bf16 MFMA) + softmax + weighted sum.
// 8 points/block, 128 cols (col = point*16 + neighbor), 4 waves.
// GEMM1: mfma(W1, a1) -> channels in rows (for bn2+writeback).
// GEMM2: mfma(a2, W2) -> logits^T: channel = lane&15, 4 NEIGHBORS in regs
//   -> softmax = 4 in-reg partials + 2-step butterfly over lane bits 4/5.
// Output staged in padded LDS (overlay a1s) -> coalesced float4 stores.
// grid (NPTS/8, NB), block 256
// ---------------------------------------------------------------------------
__global__ __launch_bounds__(256) void attn_kernel(
    const float* __restrict__ p,
    const float* __restrict__ qT, const float* __restrict__ kT, const float* __restrict__ vT,
    const int*   __restrict__ knn_idx,
    const float* __restrict__ pe_w1,
    const float* __restrict__ pe_bn_g, const float* __restrict__ pe_bn_b,
    const float* __restrict__ pe_bn_m, const float* __restrict__ pe_bn_v,
    const float* __restrict__ pe_w2, const float* __restrict__ pe_b2,
    const float* __restrict__ bn1g, const float* __restrict__ bn1b,
    const float* __restrict__ bn1m, const float* __restrict__ bn1v,
    const float* __restrict__ at_w1,
    const float* __restrict__ bn2g, const float* __restrict__ bn2b,
    const float* __restrict__ bn2m, const float* __restrict__ bn2v,
    const float* __restrict__ at_w2, const float* __restrict__ at_b2,
    float* __restrict__ y)
{
    const int bb = blockIdx.y;
    const int i0 = blockIdx.x * 8;
    const int t  = threadIdx.x;
    const int w  = t >> 6;          // wave 0..3
    const int l  = t & 63;          // lane
    const int lm = t & 15;          // lane&15
    const int lq = l >> 4;          // quarter-wave 0..3

    __shared__ __align__(16) unsigned short a1s[128 * 128];   // 32 KB bf16 [col][k^swz]
    __shared__ __align__(16) float hbuf[3][128];
    __shared__ __align__(16) int   nidx[128];
    __shared__ __align__(16) float sc1[128], sh1[128], sc2[128], sh2[128];
    __shared__ __align__(16) float pw2t[3][128], pb2s[128], ab2s[128];

    float* __restrict__ ybuf = (float*)a1s;   // [128][12] fp32 overlay (epilogue)

    // ---- phase 0: params + neighbor indices ----
    if (t < 128) {
        int c = t;
        float s1 = bn1g[c] / sqrtf(bn1v[c] + BN_EPS);
        sc1[c] = s1; sh1[c] = bn1b[c] - bn1m[c] * s1;
        float s2 = bn2g[c] / sqrtf(bn2v[c] + BN_EPS);
        sc2[c] = s2; sh2[c] = bn2b[c] - bn2m[c] * s2;
        pw2t[0][c] = pe_w2[c * 3 + 0];
        pw2t[1][c] = pe_w2[c * 3 + 1];
        pw2t[2][c] = pe_w2[c * 3 + 2];
        pb2s[c] = pe_b2[c];
        ab2s[c] = at_b2[c];
    } else {
        int e = t - 128;
        nidx[e] = knn_idx[(bb * NPTS + i0 + (e >> 4)) * 16 + (e & 15)];
    }
    __syncthreads();

    // ---- phase 0b: positional-encoding hidden layer (fp32) ----
    if (t < 128) {
        int pt = t >> 4;
        int j = nidx[t];
        float pix = p[((size_t)bb * NPTS + i0 + pt) * 3 + 0];
        float piy = p[((size_t)bb * NPTS + i0 + pt) * 3 + 1];
        float piz = p[((size_t)bb * NPTS + i0 + pt) * 3 + 2];
        float rx = p[((size_t)bb * NPTS + j) * 3 + 0] - pix;
        float ry = p[((size_t)bb * NPTS + j) * 3 + 1] - piy;
        float rz = p[((size_t)bb * NPTS + j) * 3 + 2] - piz;
        #pragma unroll
        for (int o = 0; o < 3; o++) {
            float hv = pe_w1[o * 3 + 0] * rx + pe_w1[o * 3 + 1] * ry + pe_w1[o * 3 + 2] * rz;
            float sc = pe_bn_g[o] / sqrtf(pe_bn_v[o] + BN_EPS);
            float sh = pe_bn_b[o] - pe_bn_m[o] * sc;
            hbuf[o][t] = fmaxf(hv * sc + sh, 0.0f);
        }
    }
    __syncthreads();

    // ---- phase 1: a1 = relu(bn1(q - gk + n_r)) -> bf16 LDS (swizzled) ----
    {
        const int c0 = 2 * l, c1 = 2 * l + 1;
        const float s1a = sc1[c0], b1a = sh1[c0], s1b = sc1[c1], b1b = sh1[c1];
        const float pwa0 = pw2t[0][c0], pwa1 = pw2t[1][c0], pwa2 = pw2t[2][c0], pba = pb2s[c0];
        const float pwb0 = pw2t[0][c1], pwb1 = pw2t[1][c1], pwb2 = pw2t[2][c1], pbb = pb2s[c1];
        unsigned* a1u = (unsigned*)a1s;
        for (int it = 0; it < 32; ++it) {
            int col = w + 4 * it;
            int pt  = col >> 4;
            int j   = nidx[col];
            float2 qv2 = *(const float2*)&qT[((size_t)(bb * NPTS + i0 + pt)) * NC + c0];
            float2 kv2 = *(const float2*)&kT[((size_t)(bb * NPTS + j)) * NC + c0];
            float h0 = hbuf[0][col], h1 = hbuf[1][col], h2 = hbuf[2][col];
            float nra = pwa0 * h0 + pwa1 * h1 + pwa2 * h2 + pba;
            float nrb = pwb0 * h0 + pwb1 * h1 + pwb2 * h2 + pbb;
            float a0 = fmaxf((qv2.x - kv2.x + nra) * s1a + b1a, 0.0f);
            float a1v = fmaxf((qv2.y - kv2.y + nrb) * s1b + b1b, 0.0f);
            a1u[col * 64 + (l ^ ((col & 7) << 2))] = pack2bf(a0, a1v);
        }
    }

    // ---- W1 fragments (fp32->bf16 in regs; L2-resident, all blocks share) ----
    v8s wf[2][4];
    #pragma unroll
    for (int rt = 0; rt < 2; rt++)
        #pragma unroll
        for (int ks = 0; ks < 4; ks++)
            wf[rt][ks] = load_wfrag_bf16(at_w1 + (size_t)(w * 32 + rt * 16 + lm) * NC + ks * 32 + lq * 8);

    __syncthreads();

    // ---- GEMM1: a2 = at_w1 @ a1 (MFMA, channels in rows) ----
    v4f acc[2][8];
    #pragma unroll
    for (int rt = 0; rt < 2; rt++)
        #pragma unroll
        for (int ct = 0; ct < 8; ct++) acc[rt][ct] = (v4f)0.0f;

    #pragma unroll
    for (int ct = 0; ct < 8; ct++) {
        const int col = ct * 16 + lm;
        const int sw8 = (col & 7) << 3;
        #pragma unroll
        for (int ks = 0; ks < 4; ks++) {
            v8s b = *(const v8s*)&a1s[col * 128 + ((ks * 32 + lq * 8) ^ sw8)];
            acc[0][ct] = __builtin_amdgcn_mfma_f32_16x16x32_bf16(wf[0][ks], b, acc[0][ct], 0, 0, 0);
            acc[1][ct] = __builtin_amdgcn_mfma_f32_16x16x32_bf16(wf[1][ks], b, acc[1][ct], 0, 0, 0);
        }
    }
    __syncthreads();   // all GEMM1 reads done before overwrite

    // ---- bn2 + relu -> bf16 back into same LDS buffer ----
    #pragma unroll
    for (int rt = 0; rt < 2; rt++) {
        const int r0 = w * 32 + rt * 16 + lq * 4;
        float4 scv = *(const float4*)&sc2[r0];
        float4 shv = *(const float4*)&sh2[r0];
        #pragma unroll
        for (int ct = 0; ct < 8; ct++) {
            const int col = ct * 16 + lm;
            v4f v = acc[rt][ct];
            float x0 = fmaxf(v[0] * scv.x + shv.x, 0.0f);
            float x1 = fmaxf(v[1] * scv.y + shv.y, 0.0f);
            float x2 = fmaxf(v[2] * scv.z + shv.z, 0.0f);
            float x3 = fmaxf(v[3] * scv.w + shv.w, 0.0f);
            *(uint2*)&a1s[col * 128 + (r0 ^ ((col & 7) << 3))] =
                make_uint2(pack2bf(x0, x1), pack2bf(x2, x3));
        }
    }

    // ---- W2 fragments ----
    #pragma unroll
    for (int rt = 0; rt < 2; rt++)
        #pragma unroll
        for (int ks = 0; ks < 4; ks++)
            wf[rt][ks] = load_wfrag_bf16(at_w2 + (size_t)(w * 32 + rt * 16 + lm) * NC + ks * 32 + lq * 8);

    __syncthreads();

    // ---- GEMM2 (SWAPPED operands): logits^T = a2^T @ W2^T ----
    // acc[rt][ct]: rows = 4 neighbors (lq*4+reg) of point ct, col = channel lm.
    #pragma unroll
    for (int rt = 0; rt < 2; rt++)
        #pragma unroll
        for (int ct = 0; ct < 8; ct++) acc[rt][ct] = (v4f)0.0f;

    #pragma unroll
    for (int ct = 0; ct < 8; ct++) {
        const int col = ct * 16 + lm;
        const int sw8 = (col & 7) << 3;
        #pragma unroll
        for (int ks = 0; ks < 4; ks++) {
            v8s b = *(const v8s*)&a1s[col * 128 + ((ks * 32 + lq * 8) ^ sw8)];
            acc[0][ct] = __builtin_amdgcn_mfma_f32_16x16x32_bf16(b, wf[0][ks], acc[0][ct], 0, 0, 0);
            acc[1][ct] = __builtin_amdgcn_mfma_f32_16x16x32_bf16(b, wf[1][ks], acc[1][ct], 0, 0, 0);
        }
    }
    __syncthreads();   // all GEMM2 LDS reads done before ybuf overlay

    // ---- softmax over neighbors + weighted sum (4 in-reg + 2-step butterfly) ----
    #pragma unroll
    for (int ct = 0; ct < 8; ct++) {
        const int colb = ct * 16 + lq * 4;          // 4 neighbor cols of point ct
        float4 h0 = *(const float4*)&hbuf[0][colb];
        float4 h1 = *(const float4*)&hbuf[1][colb];
        float4 h2 = *(const float4*)&hbuf[2][colb];
        int j0 = nidx[colb + 0], j1 = nidx[colb + 1];
        int j2 = nidx[colb + 2], j3 = nidx[colb + 3];
        #pragma unroll
        for (int rt = 0; rt < 2; rt++) {
            const int c = w * 32 + rt * 16 + lm;
            const float pw0 = pw2t[0][c], pw1 = pw2t[1][c], pw2v = pw2t[2][c];
            const float pb = pb2s[c], b2 = ab2s[c];
            v4f lg = acc[rt][ct];
            float v0 = vT[((size_t)(bb * NPTS + j0)) * NC + c];
            float v1 = vT[((size_t)(bb * NPTS + j1)) * NC + c];
            float v2 = vT[((size_t)(bb * NPTS + j2)) * NC + c];
            float v3 = vT[((size_t)(bb * NPTS + j3)) * NC + c];
            float e0 = __expf(lg[0] + b2);
            float e1 = __expf(lg[1] + b2);
            float e2 = __expf(lg[2] + b2);
            float e3 = __expf(lg[3] + b2);
            float n0 = pw0 * h0.x + pw1 * h1.x + pw2v * h2.x + pb;
            float n1 = pw0 * h0.y + pw1 * h1.y + pw2v * h2.y + pb;
            float n2 = pw0 * h0.z + pw1 * h1.z + pw2v * h2.z + pb;
            float n3 = pw0 * h0.w + pw1 * h1.w + pw2v * h2.w + pb;
            float se = (e0 + e1) + (e2 + e3);
            float pr = (e0 * (v0 + n0) + e1 * (v1 + n1)) + (e2 * (v2 + n2) + e3 * (v3 + n3));
            se += __shfl_xor(se, 16); pr += __shfl_xor(pr, 16);
            se += __shfl_xor(se, 32); pr += __shfl_xor(pr, 32);
            if (lq == 0) ybuf[c * 12 + ct] = pr / se;
        }
    }
    __syncthreads();

    // ---- coalesced output: [c][8 points] -> y[b][c][n] float4 stores ----
    {
        int c = t >> 1, half = t & 1;
        float4 o = *(const float4*)&ybuf[c * 12 + half * 4];
        *(float4*)&y[((size_t)bb * NC + c) * NPTS + i0 + half * 4] = o;
    }
}

// ---------------------------------------------------------------------------
extern "C" void kernel_launch(void* const* d_in, const int* in_sizes, int n_in,
                              void* d_out, int out_size, void* d_ws, size_t ws_size,
                              hipStream_t stream) {
    const float* p     = (const float*)d_in[0];
    const float* x     = (const float*)d_in[1];
    const float* wq    = (const float*)d_in[2];
    const float* bq    = (const float*)d_in[3];
    const float* wk    = (const float*)d_in[4];
    const float* bk    = (const float*)d_in[5];
    const float* wv    = (const float*)d_in[6];
    const float* bv    = (const float*)d_in[7];
    const float* pe_w1 = (const float*)d_in[8];
    const float* pe_bn_g = (const float*)d_in[9];
    const float* pe_bn_b = (const float*)d_in[10];
    const float* pe_bn_m = (const float*)d_in[11];
    const float* pe_bn_v = (const float*)d_in[12];
    const float* pe_w2 = (const float*)d_in[13];
    const float* pe_b2 = (const float*)d_in[14];
    const float* bn1g  = (const float*)d_in[15];
    const float* bn1b  = (const float*)d_in[16];
    const float* bn1m  = (const float*)d_in[17];
    const float* bn1v  = (const float*)d_in[18];
    const float* at_w1 = (const float*)d_in[19];
    const float* bn2g  = (const float*)d_in[20];
    const float* bn2b  = (const float*)d_in[21];
    const float* bn2m  = (const float*)d_in[22];
    const float* bn2v  = (const float*)d_in[23];
    const float* at_w2 = (const float*)d_in[24];
    const float* at_b2 = (const float*)d_in[25];
    float* out = (float*)d_out;

    // workspace layout (25 MB total), X = ws + 1MB:
    //   [idx 1MB][ X: qT 8MB | kT 8MB | vT 8MB ]
    // kNN scratch aliases X (all kNN kernels run before qkv writes qT/kT/vT).
    char* base = (char*)d_ws;
    int*   idx   = (int*)base;
    char*  X     = base + (1u << 20);
    float* qT    = (float*)X;
    float* kT    = qT + (size_t)NB * NPTS * NC;
    float* vT    = kT + (size_t)NB * NPTS * NC;
    float* partd = (float*)X;
    int*   pidx  = (int*)X;
    unsigned* pcnt = (unsigned*)(X + (size_t)18 * (1u << 20));
    float* thr   = (float*)(X + (size_t)23 * (1u << 20) + (1u << 19));

    knnA_kernel<<<dim3(NPTS / 256, NSPLIT, NB), 256, 0, stream>>>(p, partd);
    knnM_kernel<<<dim3(NB * NPTS / 256), 256, 0, stream>>>(partd, thr);
    knnB_kernel<<<dim3(NPTS / 256, NSPLIT, NB), 256, 0, stream>>>(p, thr, pidx, pcnt);
    knnF_kernel<<<dim3(NB * NPTS / 256), 256, 0, stream>>>(p, thr, pidx, pcnt, idx);
    qkv_kernel<<<dim3(NPTS / 64, 3, NB), 256, 0, stream>>>(
        x, wq, bq, wk, bk, wv, bv, qT, kT, vT);
    attn_kernel<<<dim3(NPTS / 8, NB), 256, 0, stream>>>(
        p, qT, kT, vT, idx,
        pe_w1, pe_bn_g, pe_bn_b, pe_bn_m, pe_bn_v, pe_w2, pe_b2,
        bn1g, bn1b, bn1m, bn1v, at_w1,
        bn2g, bn2b, bn2m, bn2v, at_w2, at_b2, out);
}

// Round 6
// 256.002 us; speedup vs baseline: 10.2678x; 1.3230x over previous
//
#include <hip/hip_runtime.h>
#include <math.h>

#define NB    2
#define NPTS  8192
#define NC    128
#define NKN   16
#define NSPLIT 16
#define CSPLIT (NPTS / NSPLIT)   // 512
#define BN_EPS 1e-5f

typedef short  v8s __attribute__((ext_vector_type(8)));   // 8 bf16 (4 VGPRs)
typedef float  v4f __attribute__((ext_vector_type(4)));

// fp32 -> bf16 with round-to-nearest-even (scalar fallback)
__device__ __forceinline__ short bf16rne(float f) {
    unsigned u = __float_as_uint(f);
    unsigned r = (u + 0x7FFFu + ((u >> 16) & 1u)) >> 16;
    return (short)r;
}
__device__ __forceinline__ unsigned pack2bf(float a, float b) {
    return (unsigned)(unsigned short)bf16rne(a) | ((unsigned)(unsigned short)bf16rne(b) << 16);
}
__device__ __forceinline__ unsigned cvtpk_bf16(float a, float b) {
    unsigned r;
    asm("v_cvt_pk_bf16_f32 %0, %1, %2" : "=v"(r) : "v"(a), "v"(b));
    return r;   // lo = bf16(a), hi = bf16(b), RNE
}
__device__ __forceinline__ v8s frag_from4(unsigned u0, unsigned u1, unsigned u2, unsigned u3) {
    union { unsigned u[4]; v8s s; } t;
    t.u[0] = u0; t.u[1] = u1; t.u[2] = u2; t.u[3] = u3;
    return t.s;
}
__device__ __forceinline__ v8s load_wfrag_bf16(const float* __restrict__ wp) {
    float4 f0 = *(const float4*)wp;
    float4 f1 = *(const float4*)(wp + 4);
    return frag_from4(cvtpk_bf16(f0.x, f0.y), cvtpk_bf16(f0.z, f0.w),
                      cvtpk_bf16(f1.x, f1.y), cvtpk_bf16(f1.z, f1.w));
}

// unconditional sorted-insert of x into ascending d[0..15], IN PLACE:
// descending update reads only not-yet-written elements (no temp array, no movs)
#define INSERTD(XV)                                                  \
  {                                                                  \
    float x_ = (XV);                                                 \
    _Pragma("unroll")                                                \
    for (int s_ = 15; s_ >= 1; s_--)                                 \
      d[s_] = __builtin_amdgcn_fmed3f(d[s_ - 1], d[s_], x_);         \
    d[0] = fminf(d[0], x_);                                          \
  }

// ---------------------------------------------------------------------------
// Kernel 1: q/k/v via MFMA. Out tile qT[pt][ch] = mfma(A=x^T frag, B=w frag).
// x staged as packed-bf16 pairs xspk[kpair][pt] (coalesced read, conflict-free
// write, 2-way-free frag read with pad 66). A-frags loaded once, reused for
// all 3 mats. grid (NPTS/64, NB), block 256 (4 waves; wave w -> ch [32w,32w+32)).
// ---------------------------------------------------------------------------
__global__ __launch_bounds__(256) void qkv_kernel(
    const float* __restrict__ x,
    const float* __restrict__ wq, const float* __restrict__ bq,
    const float* __restrict__ wk, const float* __restrict__ bk,
    const float* __restrict__ wv, const float* __restrict__ bv,
    float* __restrict__ qT, float* __restrict__ kT, float* __restrict__ vT)
{
    const int bb = blockIdx.y;
    const int i0 = blockIdx.x * 64;
    const int t  = threadIdx.x;
    const int w  = t >> 6;
    const int l  = t & 63;
    const int lm = l & 15;
    const int lq = l >> 4;

    __shared__ __align__(16) unsigned xspk[64][66];   // 16.9 KB

    // stage: u32 = (bf16(x[2kp+1]) << 16) | bf16(x[2kp]) at [kp][pt]
    #pragma unroll
    for (int kp = w; kp < 64; kp += 4) {
        float v0 = x[((size_t)bb * NC + 2 * kp)     * NPTS + i0 + l];
        float v1 = x[((size_t)bb * NC + 2 * kp + 1) * NPTS + i0 + l];
        xspk[kp][l] = cvtpk_bf16(v0, v1);
    }
    __syncthreads();

    // A-frags: lane lm = pt row, k = ks*32 + lq*8 + e  (kpairs ks*16+lq*4+0..3)
    v8s af[4][4];
    #pragma unroll
    for (int Mt = 0; Mt < 4; Mt++) {
        #pragma unroll
        for (int ks = 0; ks < 4; ks++) {
            const int pt  = Mt * 16 + lm;
            const int kp0 = ks * 16 + lq * 4;
            af[Mt][ks] = frag_from4(xspk[kp0][pt], xspk[kp0 + 1][pt],
                                    xspk[kp0 + 2][pt], xspk[kp0 + 3][pt]);
        }
    }

    const int cb = w * 32;
    const float* Ws[3] = { wq, wk, wv };
    const float* Bs[3] = { bq, bk, bv };
    float*       Os[3] = { qT, kT, vT };

    #pragma unroll
    for (int mat = 0; mat < 3; mat++) {
        const float* __restrict__ W = Ws[mat];
        v8s bfg[2][4];
        #pragma unroll
        for (int nt = 0; nt < 2; nt++)
            #pragma unroll
            for (int ks = 0; ks < 4; ks++)
                bfg[nt][ks] = load_wfrag_bf16(W + (size_t)(cb + nt * 16 + lm) * NC + ks * 32 + lq * 8);
        const float b0 = Bs[mat][cb + lm];
        const float b1 = Bs[mat][cb + 16 + lm];

        v4f acc[4][2];
        #pragma unroll
        for (int Mt = 0; Mt < 4; Mt++) { acc[Mt][0] = (v4f)0.0f; acc[Mt][1] = (v4f)0.0f; }

        #pragma unroll
        for (int Mt = 0; Mt < 4; Mt++)
            #pragma unroll
            for (int ks = 0; ks < 4; ks++) {
                acc[Mt][0] = __builtin_amdgcn_mfma_f32_16x16x32_bf16(af[Mt][ks], bfg[0][ks], acc[Mt][0], 0, 0, 0);
                acc[Mt][1] = __builtin_amdgcn_mfma_f32_16x16x32_bf16(af[Mt][ks], bfg[1][ks], acc[Mt][1], 0, 0, 0);
            }

        float* __restrict__ O = Os[mat];
        #pragma unroll
        for (int Mt = 0; Mt < 4; Mt++)
            #pragma unroll
            for (int nt = 0; nt < 2; nt++) {
                const float bv_ = nt ? b1 : b0;
                #pragma unroll
                for (int r = 0; r < 4; r++)
                    O[((size_t)bb * NPTS + i0 + Mt * 16 + lq * 4 + r) * NC + cb + nt * 16 + lm] =
                        acc[Mt][nt][r] + bv_;
            }
    }
}

// ---------------------------------------------------------------------------
// Kernel 2a: kNN phase A — per (query, split) top-16 DISTANCES only.
// ---------------------------------------------------------------------------
__global__ __launch_bounds__(256) void knnA_kernel(
    const float* __restrict__ p,      // [NB][NPTS][3]
    float* __restrict__ partd)        // [NB][NSPLIT][NPTS][16]
{
    const int bb = blockIdx.z, sp = blockIdx.y, q0 = blockIdx.x * 256;
    const int t  = threadIdx.x;

    __shared__ float4 cand[CSPLIT];   // 8 KB
    const float* __restrict__ pc = p + ((size_t)bb * NPTS + sp * CSPLIT) * 3;
    for (int j = t; j < CSPLIT; j += 256) {
        float cx = pc[j * 3 + 0], cy = pc[j * 3 + 1], cz = pc[j * 3 + 2];
        float s  = __fadd_rn(__fadd_rn(__fmul_rn(cx, cx), __fmul_rn(cy, cy)),
                             __fmul_rn(cz, cz));
        cand[j] = make_float4(cx, cy, cz, s);
    }
    __syncthreads();

    const int i = q0 + t;
    const float qx = p[((size_t)bb * NPTS + i) * 3 + 0];
    const float qy = p[((size_t)bb * NPTS + i) * 3 + 1];
    const float qz = p[((size_t)bb * NPTS + i) * 3 + 2];
    const float sqi = __fadd_rn(__fadd_rn(__fmul_rn(qx, qx), __fmul_rn(qy, qy)),
                                __fmul_rn(qz, qz));

    float d[16];
    #pragma unroll
    for (int s = 0; s < 16; s++) d[s] = 3.4e38f;

    #pragma unroll 2
    for (int j = 0; j < CSPLIT; j++) {
        float4 c = cand[j];
        float dot = __fadd_rn(__fadd_rn(__fmul_rn(qx, c.x), __fmul_rn(qy, c.y)),
                              __fmul_rn(qz, c.z));
        float d2 = __fsub_rn(__fadd_rn(sqi, c.w), __fmul_rn(2.0f, dot));
        INSERTD(d2);
    }

    float* __restrict__ row = partd + (((size_t)bb * NSPLIT + sp) * NPTS + i) * 16;
    #pragma unroll
    for (int s = 0; s < 16; s += 4)
        *(float4*)&row[s] = make_float4(d[s], d[s + 1], d[s + 2], d[s + 3]);
}

// ---------------------------------------------------------------------------
// Kernel 2b: merge per-split distance lists -> 16th-smallest threshold.
// ---------------------------------------------------------------------------
__global__ __launch_bounds__(256) void knnM_kernel(
    const float* __restrict__ partd,
    float* __restrict__ thr)          // [NB*NPTS]
{
    const int gid = blockIdx.x * 256 + threadIdx.x;
    const int bb  = gid >> 13;
    const int i   = gid & (NPTS - 1);

    float d[16];
    const float* __restrict__ r0 = partd + (((size_t)bb * NSPLIT + 0) * NPTS + i) * 16;
    #pragma unroll
    for (int s = 0; s < 16; s += 4) {
        float4 v = *(const float4*)&r0[s];
        d[s] = v.x; d[s + 1] = v.y; d[s + 2] = v.z; d[s + 3] = v.w;
    }
    for (int sp = 1; sp < NSPLIT; sp++) {
        const float* __restrict__ r = partd + (((size_t)bb * NSPLIT + sp) * NPTS + i) * 16;
        #pragma unroll
        for (int s = 0; s < 16; s += 4) {
            float4 v = *(const float4*)&r[s];
            INSERTD(v.x); INSERTD(v.y); INSERTD(v.z); INSERTD(v.w);
        }
    }
    thr[gid] = d[15];
}

// ---------------------------------------------------------------------------
// Kernel 2c: threshold re-scan — append candidate indices with d2 <= thr.
// ---------------------------------------------------------------------------
__global__ __launch_bounds__(256) void knnB_kernel(
    const float* __restrict__ p,
    const float* __restrict__ thr,
    int* __restrict__ pidx,           // [NB][NSPLIT][NPTS][16]
    unsigned* __restrict__ pcnt)      // [NB][NSPLIT][NPTS]
{
    const int bb = blockIdx.z, sp = blockIdx.y, q0 = blockIdx.x * 256;
    const int t  = threadIdx.x;

    __shared__ float4 cand[CSPLIT];
    const float* __restrict__ pc = p + ((size_t)bb * NPTS + sp * CSPLIT) * 3;
    for (int j = t; j < CSPLIT; j += 256) {
        float cx = pc[j * 3 + 0], cy = pc[j * 3 + 1], cz = pc[j * 3 + 2];
        float s  = __fadd_rn(__fadd_rn(__fmul_rn(cx, cx), __fmul_rn(cy, cy)),
                             __fmul_rn(cz, cz));
        cand[j] = make_float4(cx, cy, cz, s);
    }
    __syncthreads();

    const int i = q0 + t;
    const float qx = p[((size_t)bb * NPTS + i) * 3 + 0];
    const float qy = p[((size_t)bb * NPTS + i) * 3 + 1];
    const float qz = p[((size_t)bb * NPTS + i) * 3 + 2];
    const float sqi = __fadd_rn(__fadd_rn(__fmul_rn(qx, qx), __fmul_rn(qy, qy)),
                                __fmul_rn(qz, qz));
    const float thv = thr[bb * NPTS + i];

    int cnt = 0;
    int* __restrict__ row = pidx + (((size_t)bb * NSPLIT + sp) * NPTS + i) * 16;
    for (int j = 0; j < CSPLIT; j++) {
        float4 c = cand[j];
        float dot = __fadd_rn(__fadd_rn(__fmul_rn(qx, c.x), __fmul_rn(qy, c.y)),
                              __fmul_rn(qz, c.z));
        float d2 = __fsub_rn(__fadd_rn(sqi, c.w), __fmul_rn(2.0f, dot));
        if (d2 <= thv && cnt < 16) { row[cnt] = sp * CSPLIT + j; cnt++; }
    }
    pcnt[((size_t)bb * NSPLIT + sp) * NPTS + i] = cnt;
}

// ---------------------------------------------------------------------------
// Kernel 2d: finalize — concat per-split appends (ascending index order).
// ---------------------------------------------------------------------------
__global__ __launch_bounds__(256) void knnF_kernel(
    const float* __restrict__ p,
    const float* __restrict__ thr,
    const int* __restrict__ pidx,
    const unsigned* __restrict__ pcnt,
    int* __restrict__ knn_idx)        // [NB][NPTS][16]
{
    const int gid = blockIdx.x * 256 + threadIdx.x;
    const int bb  = gid >> 13;
    const int i   = gid & (NPTS - 1);

    int cnts[NSPLIT];
    int total = 0;
    #pragma unroll
    for (int sp = 0; sp < NSPLIT; sp++) {
        cnts[sp] = (int)pcnt[((size_t)bb * NSPLIT + sp) * NPTS + i];
        total += cnts[sp];
    }
    int* __restrict__ out = knn_idx + (size_t)gid * 16;

    if (total == 16) {
        int w = 0;
        for (int sp = 0; sp < NSPLIT; sp++) {
            const int* __restrict__ r = pidx + (((size_t)bb * NSPLIT + sp) * NPTS + i) * 16;
            for (int e = 0; e < cnts[sp]; e++) out[w++] = r[e];
        }
    } else {
        const float qx = p[((size_t)bb * NPTS + i) * 3 + 0];
        const float qy = p[((size_t)bb * NPTS + i) * 3 + 1];
        const float qz = p[((size_t)bb * NPTS + i) * 3 + 2];
        const float sqi = __fadd_rn(__fadd_rn(__fmul_rn(qx, qx), __fmul_rn(qy, qy)),
                                    __fmul_rn(qz, qz));
        const float thv = thr[bb * NPTS + i];
        int w = 0;
        for (int pass = 0; pass < 2; pass++) {
            for (int sp = 0; sp < NSPLIT && w < 16; sp++) {
                const int* __restrict__ r = pidx + (((size_t)bb * NSPLIT + sp) * NPTS + i) * 16;
                for (int e = 0; e < cnts[sp] && w < 16; e++) {
                    int j = r[e];
                    float cx = p[((size_t)bb * NPTS + j) * 3 + 0];
                    float cy = p[((size_t)bb * NPTS + j) * 3 + 1];
                    float cz = p[((size_t)bb * NPTS + j) * 3 + 2];
                    float sqj = __fadd_rn(__fadd_rn(__fmul_rn(cx, cx), __fmul_rn(cy, cy)),
                                          __fmul_rn(cz, cz));
                    float dot = __fadd_rn(__fadd_rn(__fmul_rn(qx, cx), __fmul_rn(qy, cy)),
                                          __fmul_rn(qz, cz));
                    float d2 = __fsub_rn(__fadd_rn(sqi, sqj), __fmul_rn(2.0f, dot));
                    bool take = (pass == 0) ? (d2 < thv) : (d2 == thv);
                    if (take) out[w++] = j;
                }
            }
        }
    }
}

// ---------------------------------------------------------------------------
// Kernel 3: fused PE-MLP + attention MLP (bf16 MFMA) + softmax + weighted sum.
// (unchanged from round 5)
// ---------------------------------------------------------------------------
__global__ __launch_bounds__(256) void attn_kernel(
    const float* __restrict__ p,
    const float* __restrict__ qT, const float* __restrict__ kT, const float* __restrict__ vT,
    const int*   __restrict__ knn_idx,
    const float* __restrict__ pe_w1,
    const float* __restrict__ pe_bn_g, const float* __restrict__ pe_bn_b,
    const float* __restrict__ pe_bn_m, const float* __restrict__ pe_bn_v,
    const float* __restrict__ pe_w2, const float* __restrict__ pe_b2,
    const float* __restrict__ bn1g, const float* __restrict__ bn1b,
    const float* __restrict__ bn1m, const float* __restrict__ bn1v,
    const float* __restrict__ at_w1,
    const float* __restrict__ bn2g, const float* __restrict__ bn2b,
    const float* __restrict__ bn2m, const float* __restrict__ bn2v,
    const float* __restrict__ at_w2, const float* __restrict__ at_b2,
    float* __restrict__ y)
{
    const int bb = blockIdx.y;
    const int i0 = blockIdx.x * 8;
    const int t  = threadIdx.x;
    const int w  = t >> 6;          // wave 0..3
    const int l  = t & 63;          // lane
    const int lm = t & 15;          // lane&15
    const int lq = l >> 4;          // quarter-wave 0..3

    __shared__ __align__(16) unsigned short a1s[128 * 128];   // 32 KB bf16 [col][k^swz]
    __shared__ __align__(16) float hbuf[3][128];
    __shared__ __align__(16) int   nidx[128];
    __shared__ __align__(16) float sc1[128], sh1[128], sc2[128], sh2[128];
    __shared__ __align__(16) float pw2t[3][128], pb2s[128], ab2s[128];

    float* __restrict__ ybuf = (float*)a1s;   // [128][12] fp32 overlay (epilogue)

    // ---- phase 0: params + neighbor indices ----
    if (t < 128) {
        int c = t;
        float s1 = bn1g[c] / sqrtf(bn1v[c] + BN_EPS);
        sc1[c] = s1; sh1[c] = bn1b[c] - bn1m[c] * s1;
        float s2 = bn2g[c] / sqrtf(bn2v[c] + BN_EPS);
        sc2[c] = s2; sh2[c] = bn2b[c] - bn2m[c] * s2;
        pw2t[0][c] = pe_w2[c * 3 + 0];
        pw2t[1][c] = pe_w2[c * 3 + 1];
        pw2t[2][c] = pe_w2[c * 3 + 2];
        pb2s[c] = pe_b2[c];
        ab2s[c] = at_b2[c];
    } else {
        int e = t - 128;
        nidx[e] = knn_idx[(bb * NPTS + i0 + (e >> 4)) * 16 + (e & 15)];
    }
    __syncthreads();

    // ---- phase 0b: positional-encoding hidden layer (fp32) ----
    if (t < 128) {
        int pt = t >> 4;
        int j = nidx[t];
        float pix = p[((size_t)bb * NPTS + i0 + pt) * 3 + 0];
        float piy = p[((size_t)bb * NPTS + i0 + pt) * 3 + 1];
        float piz = p[((size_t)bb * NPTS + i0 + pt) * 3 + 2];
        float rx = p[((size_t)bb * NPTS + j) * 3 + 0] - pix;
        float ry = p[((size_t)bb * NPTS + j) * 3 + 1] - piy;
        float rz = p[((size_t)bb * NPTS + j) * 3 + 2] - piz;
        #pragma unroll
        for (int o = 0; o < 3; o++) {
            float hv = pe_w1[o * 3 + 0] * rx + pe_w1[o * 3 + 1] * ry + pe_w1[o * 3 + 2] * rz;
            float sc = pe_bn_g[o] / sqrtf(pe_bn_v[o] + BN_EPS);
            float sh = pe_bn_b[o] - pe_bn_m[o] * sc;
            hbuf[o][t] = fmaxf(hv * sc + sh, 0.0f);
        }
    }
    __syncthreads();

    // ---- phase 1: a1 = relu(bn1(q - gk + n_r)) -> bf16 LDS (swizzled) ----
    {
        const int c0 = 2 * l, c1 = 2 * l + 1;
        const float s1a = sc1[c0], b1a = sh1[c0], s1b = sc1[c1], b1b = sh1[c1];
        const float pwa0 = pw2t[0][c0], pwa1 = pw2t[1][c0], pwa2 = pw2t[2][c0], pba = pb2s[c0];
        const float pwb0 = pw2t[0][c1], pwb1 = pw2t[1][c1], pwb2 = pw2t[2][c1], pbb = pb2s[c1];
        unsigned* a1u = (unsigned*)a1s;
        for (int it = 0; it < 32; ++it) {
            int col = w + 4 * it;
            int pt  = col >> 4;
            int j   = nidx[col];
            float2 qv2 = *(const float2*)&qT[((size_t)(bb * NPTS + i0 + pt)) * NC + c0];
            float2 kv2 = *(const float2*)&kT[((size_t)(bb * NPTS + j)) * NC + c0];
            float h0 = hbuf[0][col], h1 = hbuf[1][col], h2 = hbuf[2][col];
            float nra = pwa0 * h0 + pwa1 * h1 + pwa2 * h2 + pba;
            float nrb = pwb0 * h0 + pwb1 * h1 + pwb2 * h2 + pbb;
            float a0 = fmaxf((qv2.x - kv2.x + nra) * s1a + b1a, 0.0f);
            float a1v = fmaxf((qv2.y - kv2.y + nrb) * s1b + b1b, 0.0f);
            a1u[col * 64 + (l ^ ((col & 7) << 2))] = pack2bf(a0, a1v);
        }
    }

    // ---- W1 fragments ----
    v8s wf[2][4];
    #pragma unroll
    for (int rt = 0; rt < 2; rt++)
        #pragma unroll
        for (int ks = 0; ks < 4; ks++)
            wf[rt][ks] = load_wfrag_bf16(at_w1 + (size_t)(w * 32 + rt * 16 + lm) * NC + ks * 32 + lq * 8);

    __syncthreads();

    // ---- GEMM1: a2 = at_w1 @ a1 (MFMA, channels in rows) ----
    v4f acc[2][8];
    #pragma unroll
    for (int rt = 0; rt < 2; rt++)
        #pragma unroll
        for (int ct = 0; ct < 8; ct++) acc[rt][ct] = (v4f)0.0f;

    #pragma unroll
    for (int ct = 0; ct < 8; ct++) {
        const int col = ct * 16 + lm;
        const int sw8 = (col & 7) << 3;
        #pragma unroll
        for (int ks = 0; ks < 4; ks++) {
            v8s b = *(const v8s*)&a1s[col * 128 + ((ks * 32 + lq * 8) ^ sw8)];
            acc[0][ct] = __builtin_amdgcn_mfma_f32_16x16x32_bf16(wf[0][ks], b, acc[0][ct], 0, 0, 0);
            acc[1][ct] = __builtin_amdgcn_mfma_f32_16x16x32_bf16(wf[1][ks], b, acc[1][ct], 0, 0, 0);
        }
    }
    __syncthreads();   // all GEMM1 reads done before overwrite

    // ---- bn2 + relu -> bf16 back into same LDS buffer ----
    #pragma unroll
    for (int rt = 0; rt < 2; rt++) {
        const int r0 = w * 32 + rt * 16 + lq * 4;
        float4 scv = *(const float4*)&sc2[r0];
        float4 shv = *(const float4*)&sh2[r0];
        #pragma unroll
        for (int ct = 0; ct < 8; ct++) {
            const int col = ct * 16 + lm;
            v4f v = acc[rt][ct];
            float x0 = fmaxf(v[0] * scv.x + shv.x, 0.0f);
            float x1 = fmaxf(v[1] * scv.y + shv.y, 0.0f);
            float x2 = fmaxf(v[2] * scv.z + shv.z, 0.0f);
            float x3 = fmaxf(v[3] * scv.w + shv.w, 0.0f);
            *(uint2*)&a1s[col * 128 + (r0 ^ ((col & 7) << 3))] =
                make_uint2(pack2bf(x0, x1), pack2bf(x2, x3));
        }
    }

    // ---- W2 fragments ----
    #pragma unroll
    for (int rt = 0; rt < 2; rt++)
        #pragma unroll
        for (int ks = 0; ks < 4; ks++)
            wf[rt][ks] = load_wfrag_bf16(at_w2 + (size_t)(w * 32 + rt * 16 + lm) * NC + ks * 32 + lq * 8);

    __syncthreads();

    // ---- GEMM2 (SWAPPED operands): logits^T = a2^T @ W2^T ----
    #pragma unroll
    for (int rt = 0; rt < 2; rt++)
        #pragma unroll
        for (int ct = 0; ct < 8; ct++) acc[rt][ct] = (v4f)0.0f;

    #pragma unroll
    for (int ct = 0; ct < 8; ct++) {
        const int col = ct * 16 + lm;
        const int sw8 = (col & 7) << 3;
        #pragma unroll
        for (int ks = 0; ks < 4; ks++) {
            v8s b = *(const v8s*)&a1s[col * 128 + ((ks * 32 + lq * 8) ^ sw8)];
            acc[0][ct] = __builtin_amdgcn_mfma_f32_16x16x32_bf16(b, wf[0][ks], acc[0][ct], 0, 0, 0);
            acc[1][ct] = __builtin_amdgcn_mfma_f32_16x16x32_bf16(b, wf[1][ks], acc[1][ct], 0, 0, 0);
        }
    }
    __syncthreads();   // all GEMM2 LDS reads done before ybuf overlay

    // ---- softmax over neighbors + weighted sum (4 in-reg + 2-step butterfly) ----
    #pragma unroll
    for (int ct = 0; ct < 8; ct++) {
        const int colb = ct * 16 + lq * 4;          // 4 neighbor cols of point ct
        float4 h0 = *(const float4*)&hbuf[0][colb];
        float4 h1 = *(const float4*)&hbuf[1][colb];
        float4 h2 = *(const float4*)&hbuf[2][colb];
        int j0 = nidx[colb + 0], j1 = nidx[colb + 1];
        int j2 = nidx[colb + 2], j3 = nidx[colb + 3];
        #pragma unroll
        for (int rt = 0; rt < 2; rt++) {
            const int c = w * 32 + rt * 16 + lm;
            const float pw0 = pw2t[0][c], pw1 = pw2t[1][c], pw2v = pw2t[2][c];
            const float pb = pb2s[c], b2 = ab2s[c];
            v4f lg = acc[rt][ct];
            float v0 = vT[((size_t)(bb * NPTS + j0)) * NC + c];
            float v1 = vT[((size_t)(bb * NPTS + j1)) * NC + c];
            float v2 = vT[((size_t)(bb * NPTS + j2)) * NC + c];
            float v3 = vT[((size_t)(bb * NPTS + j3)) * NC + c];
            float e0 = __expf(lg[0] + b2);
            float e1 = __expf(lg[1] + b2);
            float e2 = __expf(lg[2] + b2);
            float e3 = __expf(lg[3] + b2);
            float n0 = pw0 * h0.x + pw1 * h1.x + pw2v * h2.x + pb;
            float n1 = pw0 * h0.y + pw1 * h1.y + pw2v * h2.y + pb;
            float n2 = pw0 * h0.z + pw1 * h1.z + pw2v * h2.z + pb;
            float n3 = pw0 * h0.w + pw1 * h1.w + pw2v * h2.w + pb;
            float se = (e0 + e1) + (e2 + e3);
            float pr = (e0 * (v0 + n0) + e1 * (v1 + n1)) + (e2 * (v2 + n2) + e3 * (v3 + n3));
            se += __shfl_xor(se, 16); pr += __shfl_xor(pr, 16);
            se += __shfl_xor(se, 32); pr += __shfl_xor(pr, 32);
            if (lq == 0) ybuf[c * 12 + ct] = pr / se;
        }
    }
    __syncthreads();

    // ---- coalesced output: [c][8 points] -> y[b][c][n] float4 stores ----
    {
        int c = t >> 1, half = t & 1;
        float4 o = *(const float4*)&ybuf[c * 12 + half * 4];
        *(float4*)&y[((size_t)bb * NC + c) * NPTS + i0 + half * 4] = o;
    }
}

// ---------------------------------------------------------------------------
extern "C" void kernel_launch(void* const* d_in, const int* in_sizes, int n_in,
                              void* d_out, int out_size, void* d_ws, size_t ws_size,
                              hipStream_t stream) {
    const float* p     = (const float*)d_in[0];
    const float* x     = (const float*)d_in[1];
    const float* wq    = (const float*)d_in[2];
    const float* bq    = (const float*)d_in[3];
    const float* wk    = (const float*)d_in[4];
    const float* bk    = (const float*)d_in[5];
    const float* wv    = (const float*)d_in[6];
    const float* bv    = (const float*)d_in[7];
    const float* pe_w1 = (const float*)d_in[8];
    const float* pe_bn_g = (const float*)d_in[9];
    const float* pe_bn_b = (const float*)d_in[10];
    const float* pe_bn_m = (const float*)d_in[11];
    const float* pe_bn_v = (const float*)d_in[12];
    const float* pe_w2 = (const float*)d_in[13];
    const float* pe_b2 = (const float*)d_in[14];
    const float* bn1g  = (const float*)d_in[15];
    const float* bn1b  = (const float*)d_in[16];
    const float* bn1m  = (const float*)d_in[17];
    const float* bn1v  = (const float*)d_in[18];
    const float* at_w1 = (const float*)d_in[19];
    const float* bn2g  = (const float*)d_in[20];
    const float* bn2b  = (const float*)d_in[21];
    const float* bn2m  = (const float*)d_in[22];
    const float* bn2v  = (const float*)d_in[23];
    const float* at_w2 = (const float*)d_in[24];
    const float* at_b2 = (const float*)d_in[25];
    float* out = (float*)d_out;

    // workspace layout (25 MB total), X = ws + 1MB:
    //   [idx 1MB][ X: qT 8MB | kT 8MB | vT 8MB ]
    // kNN scratch aliases X (all kNN kernels run before qkv writes qT/kT/vT).
    char* base = (char*)d_ws;
    int*   idx   = (int*)base;
    char*  X     = base + (1u << 20);
    float* qT    = (float*)X;
    float* kT    = qT + (size_t)NB * NPTS * NC;
    float* vT    = kT + (size_t)NB * NPTS * NC;
    float* partd = (float*)X;
    int*   pidx  = (int*)X;
    unsigned* pcnt = (unsigned*)(X + (size_t)18 * (1u << 20));
    float* thr   = (float*)(X + (size_t)23 * (1u << 20) + (1u << 19));

    knnA_kernel<<<dim3(NPTS / 256, NSPLIT, NB), 256, 0, stream>>>(p, partd);
    knnM_kernel<<<dim3(NB * NPTS / 256), 256, 0, stream>>>(partd, thr);
    knnB_kernel<<<dim3(NPTS / 256, NSPLIT, NB), 256, 0, stream>>>(p, thr, pidx, pcnt);
    knnF_kernel<<<dim3(NB * NPTS / 256), 256, 0, stream>>>(p, thr, pidx, pcnt, idx);
    qkv_kernel<<<dim3(NPTS / 64, NB), 256, 0, stream>>>(
        x, wq, bq, wk, bk, wv, bv, qT, kT, vT);
    attn_kernel<<<dim3(NPTS / 8, NB), 256, 0, stream>>>(
        p, qT, kT, vT, idx,
        pe_w1, pe_bn_g, pe_bn_b, pe_bn_m, pe_bn_v, pe_w2, pe_b2,
        bn1g, bn1b, bn1m, bn1v, at_w1,
        bn2g, bn2b, bn2m, bn2v, at_w2, at_b2, out);
}

// Round 7
// 226.257 us; speedup vs baseline: 11.6177x; 1.1315x over previous
//
#include <hip/hip_runtime.h>
#include <math.h>

#define NB    2
#define NPTS  8192
#define NC    128
#define NKN   16
#define NSPLIT_A 32
#define CSPLIT_A (NPTS / NSPLIT_A)   // 256
#define NSPLIT_B 16
#define CSPLIT_B (NPTS / NSPLIT_B)   // 512
#define BN_EPS 1e-5f

typedef short  v8s __attribute__((ext_vector_type(8)));   // 8 bf16 (4 VGPRs)
typedef float  v4f __attribute__((ext_vector_type(4)));

// fp32 -> bf16 round-to-nearest-even
__device__ __forceinline__ short bf16rne(float f) {
    unsigned u = __float_as_uint(f);
    unsigned r = (u + 0x7FFFu + ((u >> 16) & 1u)) >> 16;
    return (short)r;
}
__device__ __forceinline__ unsigned pack2bf(float a, float b) {
    return (unsigned)(unsigned short)bf16rne(a) | ((unsigned)(unsigned short)bf16rne(b) << 16);
}
__device__ __forceinline__ unsigned cvtpk_bf16(float a, float b) {
    unsigned r;
    asm("v_cvt_pk_bf16_f32 %0, %1, %2" : "=v"(r) : "v"(a), "v"(b));
    return r;
}
__device__ __forceinline__ v8s frag_from4(unsigned u0, unsigned u1, unsigned u2, unsigned u3) {
    union { unsigned u[4]; v8s s; } t;
    t.u[0] = u0; t.u[1] = u1; t.u[2] = u2; t.u[3] = u3;
    return t.s;
}
__device__ __forceinline__ v8s load_wfrag_bf16(const float* __restrict__ wp) {
    float4 f0 = *(const float4*)wp;
    float4 f1 = *(const float4*)(wp + 4);
    return frag_from4(cvtpk_bf16(f0.x, f0.y), cvtpk_bf16(f0.z, f0.w),
                      cvtpk_bf16(f1.x, f1.y), cvtpk_bf16(f1.z, f1.w));
}

// unconditional sorted-insert into ascending d[0..15], in place (exact merge)
#define INSERTD(XV)                                                  \
  {                                                                  \
    float x_ = (XV);                                                 \
    _Pragma("unroll")                                                \
    for (int s_ = 15; s_ >= 1; s_--)                                 \
      d[s_] = __builtin_amdgcn_fmed3f(d[s_ - 1], d[s_], x_);         \
    d[0] = fminf(d[0], x_);                                          \
  }

// guarded stable sorted-insert of (dist, idx) pairs (ascending, ties keep
// earlier-inserted = lower index when fed in ascending index order)
#define INSERT16(DV, JV)                                             \
  if ((DV) < ld[15]) {                                               \
    ld[15] = (DV); li[15] = (JV);                                    \
    _Pragma("unroll")                                                \
    for (int s_ = 15; s_ > 0; s_--) {                                \
      bool sw_ = ld[s_] < ld[s_ - 1];                                \
      float da_ = ld[s_ - 1], db_ = ld[s_];                          \
      ld[s_ - 1] = sw_ ? db_ : da_;                                  \
      ld[s_]     = sw_ ? da_ : db_;                                  \
      int ia_ = li[s_ - 1], ib_ = li[s_];                            \
      li[s_ - 1] = sw_ ? ib_ : ia_;                                  \
      li[s_]     = sw_ ? ia_ : ib_;                                  \
    }                                                                \
  }

// reduced ranking metric (per-query constant sqi dropped; fma contraction ok —
// knnF re-verifies with the exact reference formula)
__device__ __forceinline__ float reduced_d(float qx, float qy, float qz, float4 c) {
    float dot = fmaf(qx, c.x, fmaf(qy, c.y, qz * c.z));
    return fmaf(-2.0f, dot, c.w);
}

// ---------------------------------------------------------------------------
// Kernel 1: q/k/v via MFMA (unchanged from round 6)
// ---------------------------------------------------------------------------
__global__ __launch_bounds__(256) void qkv_kernel(
    const float* __restrict__ x,
    const float* __restrict__ wq, const float* __restrict__ bq,
    const float* __restrict__ wk, const float* __restrict__ bk,
    const float* __restrict__ wv, const float* __restrict__ bv,
    float* __restrict__ qT, float* __restrict__ kT, float* __restrict__ vT)
{
    const int bb = blockIdx.y;
    const int i0 = blockIdx.x * 64;
    const int t  = threadIdx.x;
    const int w  = t >> 6;
    const int l  = t & 63;
    const int lm = l & 15;
    const int lq = l >> 4;

    __shared__ __align__(16) unsigned xspk[64][66];

    #pragma unroll
    for (int kp = w; kp < 64; kp += 4) {
        float v0 = x[((size_t)bb * NC + 2 * kp)     * NPTS + i0 + l];
        float v1 = x[((size_t)bb * NC + 2 * kp + 1) * NPTS + i0 + l];
        xspk[kp][l] = cvtpk_bf16(v0, v1);
    }
    __syncthreads();

    v8s af[4][4];
    #pragma unroll
    for (int Mt = 0; Mt < 4; Mt++) {
        #pragma unroll
        for (int ks = 0; ks < 4; ks++) {
            const int pt  = Mt * 16 + lm;
            const int kp0 = ks * 16 + lq * 4;
            af[Mt][ks] = frag_from4(xspk[kp0][pt], xspk[kp0 + 1][pt],
                                    xspk[kp0 + 2][pt], xspk[kp0 + 3][pt]);
        }
    }

    const int cb = w * 32;
    const float* Ws[3] = { wq, wk, wv };
    const float* Bs[3] = { bq, bk, bv };
    float*       Os[3] = { qT, kT, vT };

    #pragma unroll
    for (int mat = 0; mat < 3; mat++) {
        const float* __restrict__ W = Ws[mat];
        v8s bfg[2][4];
        #pragma unroll
        for (int nt = 0; nt < 2; nt++)
            #pragma unroll
            for (int ks = 0; ks < 4; ks++)
                bfg[nt][ks] = load_wfrag_bf16(W + (size_t)(cb + nt * 16 + lm) * NC + ks * 32 + lq * 8);
        const float b0 = Bs[mat][cb + lm];
        const float b1 = Bs[mat][cb + 16 + lm];

        v4f acc[4][2];
        #pragma unroll
        for (int Mt = 0; Mt < 4; Mt++) { acc[Mt][0] = (v4f)0.0f; acc[Mt][1] = (v4f)0.0f; }

        #pragma unroll
        for (int Mt = 0; Mt < 4; Mt++)
            #pragma unroll
            for (int ks = 0; ks < 4; ks++) {
                acc[Mt][0] = __builtin_amdgcn_mfma_f32_16x16x32_bf16(af[Mt][ks], bfg[0][ks], acc[Mt][0], 0, 0, 0);
                acc[Mt][1] = __builtin_amdgcn_mfma_f32_16x16x32_bf16(af[Mt][ks], bfg[1][ks], acc[Mt][1], 0, 0, 0);
            }

        float* __restrict__ O = Os[mat];
        #pragma unroll
        for (int Mt = 0; Mt < 4; Mt++)
            #pragma unroll
            for (int nt = 0; nt < 2; nt++) {
                const float bv_ = nt ? b1 : b0;
                #pragma unroll
                for (int r = 0; r < 4; r++)
                    O[((size_t)bb * NPTS + i0 + Mt * 16 + lq * 4 + r) * NC + cb + nt * 16 + lm] =
                        acc[Mt][nt][r] + bv_;
            }
    }
}

// ---------------------------------------------------------------------------
// Kernel 2a: kNN phase A — 4 sorted-2 sublists per (query, split), reduced
// metric, 6 VALU ops/candidate. 2 queries/thread. Retains 8 values/split.
// grid (NPTS/512, NSPLIT_A, NB), block 256.
// ---------------------------------------------------------------------------
__global__ __launch_bounds__(256) void knnA_kernel(
    const float* __restrict__ p,      // [NB][NPTS][3]
    float* __restrict__ partd)        // [NB][NSPLIT_A][NPTS][8]
{
    const int bb = blockIdx.z, sp = blockIdx.y, q0 = blockIdx.x * 512;
    const int t  = threadIdx.x;

    __shared__ float4 cand[CSPLIT_A];   // 4 KB
    const float* __restrict__ pc = p + ((size_t)bb * NPTS + sp * CSPLIT_A) * 3;
    if (t < CSPLIT_A) {
        float cx = pc[t * 3 + 0], cy = pc[t * 3 + 1], cz = pc[t * 3 + 2];
        float s  = fmaf(cx, cx, fmaf(cy, cy, cz * cz));
        cand[t] = make_float4(cx, cy, cz, s);
    }
    __syncthreads();

    const int iA = q0 + t, iB = q0 + 256 + t;
    const float qAx = p[((size_t)bb * NPTS + iA) * 3 + 0];
    const float qAy = p[((size_t)bb * NPTS + iA) * 3 + 1];
    const float qAz = p[((size_t)bb * NPTS + iA) * 3 + 2];
    const float qBx = p[((size_t)bb * NPTS + iB) * 3 + 0];
    const float qBy = p[((size_t)bb * NPTS + iB) * 3 + 1];
    const float qBz = p[((size_t)bb * NPTS + iB) * 3 + 2];

    float dA[4][2], dB[4][2];
    #pragma unroll
    for (int s = 0; s < 4; s++) {
        dA[s][0] = 3.4e38f; dA[s][1] = 3.4e38f;
        dB[s][0] = 3.4e38f; dB[s][1] = 3.4e38f;
    }

    #pragma unroll 2
    for (int j = 0; j < CSPLIT_A; j += 4) {
        #pragma unroll
        for (int s = 0; s < 4; s++) {
            float4 c = cand[j + s];
            float ddA = reduced_d(qAx, qAy, qAz, c);
            dA[s][1] = __builtin_amdgcn_fmed3f(dA[s][0], dA[s][1], ddA);
            dA[s][0] = fminf(dA[s][0], ddA);
            float ddB = reduced_d(qBx, qBy, qBz, c);
            dB[s][1] = __builtin_amdgcn_fmed3f(dB[s][0], dB[s][1], ddB);
            dB[s][0] = fminf(dB[s][0], ddB);
        }
    }

    float* __restrict__ rowA = partd + (((size_t)bb * NSPLIT_A + sp) * NPTS + iA) * 8;
    float* __restrict__ rowB = partd + (((size_t)bb * NSPLIT_A + sp) * NPTS + iB) * 8;
    *(float4*)&rowA[0] = make_float4(dA[0][0], dA[0][1], dA[1][0], dA[1][1]);
    *(float4*)&rowA[4] = make_float4(dA[2][0], dA[2][1], dA[3][0], dA[3][1]);
    *(float4*)&rowB[0] = make_float4(dB[0][0], dB[0][1], dB[1][0], dB[1][1]);
    *(float4*)&rowB[4] = make_float4(dB[2][0], dB[2][1], dB[3][0], dB[3][1]);
}

// ---------------------------------------------------------------------------
// Kernel 2b: merge retained values -> conservative threshold (reduced space).
// thr >= true 16th-smallest; inflated to cover cross-kernel fp rounding.
// grid (NB*NPTS/256), block 256.
// ---------------------------------------------------------------------------
__global__ __launch_bounds__(256) void knnM_kernel(
    const float* __restrict__ partd,
    float* __restrict__ thr)          // [NB*NPTS]
{
    const int gid = blockIdx.x * 256 + threadIdx.x;
    const int bb  = gid >> 13;
    const int i   = gid & (NPTS - 1);

    float d[16];
    #pragma unroll
    for (int s = 0; s < 16; s++) d[s] = 3.4e38f;

    for (int sp = 0; sp < NSPLIT_A; sp++) {
        const float* __restrict__ r = partd + (((size_t)bb * NSPLIT_A + sp) * NPTS + i) * 8;
        float4 v0 = *(const float4*)&r[0];
        float4 v1 = *(const float4*)&r[4];
        INSERTD(v0.x); INSERTD(v0.y); INSERTD(v0.z); INSERTD(v0.w);
        INSERTD(v1.x); INSERTD(v1.y); INSERTD(v1.z); INSERTD(v1.w);
    }
    thr[gid] = d[15] + (4e-5f + 1e-5f * fabsf(d[15]));
}

// ---------------------------------------------------------------------------
// Kernel 2c: threshold re-scan (reduced metric) — collect candidate indices.
// Records TRUE pass count (may exceed 16; only first 16 stored).
// grid (NPTS/256, NSPLIT_B, NB), block 256.
// ---------------------------------------------------------------------------
__global__ __launch_bounds__(256) void knnB_kernel(
    const float* __restrict__ p,
    const float* __restrict__ thr,
    int* __restrict__ pidx,           // [NB][NSPLIT_B][NPTS][16]
    unsigned* __restrict__ pcnt)      // [NB][NSPLIT_B][NPTS]
{
    const int bb = blockIdx.z, sp = blockIdx.y, q0 = blockIdx.x * 256;
    const int t  = threadIdx.x;

    __shared__ float4 cand[CSPLIT_B];   // 8 KB
    const float* __restrict__ pc = p + ((size_t)bb * NPTS + sp * CSPLIT_B) * 3;
    for (int j = t; j < CSPLIT_B; j += 256) {
        float cx = pc[j * 3 + 0], cy = pc[j * 3 + 1], cz = pc[j * 3 + 2];
        float s  = fmaf(cx, cx, fmaf(cy, cy, cz * cz));
        cand[j] = make_float4(cx, cy, cz, s);
    }
    __syncthreads();

    const int i = q0 + t;
    const float qx = p[((size_t)bb * NPTS + i) * 3 + 0];
    const float qy = p[((size_t)bb * NPTS + i) * 3 + 1];
    const float qz = p[((size_t)bb * NPTS + i) * 3 + 2];
    const float thv = thr[bb * NPTS + i];

    int cnt = 0;
    int* __restrict__ row = pidx + (((size_t)bb * NSPLIT_B + sp) * NPTS + i) * 16;
    #pragma unroll 4
    for (int j = 0; j < CSPLIT_B; j++) {
        float dd = reduced_d(qx, qy, qz, cand[j]);
        if (dd <= thv) {
            if (cnt < 16) row[cnt] = sp * CSPLIT_B + j;
            cnt++;
        }
    }
    pcnt[((size_t)bb * NSPLIT_B + sp) * NPTS + i] = (unsigned)cnt;
}

// ---------------------------------------------------------------------------
// Kernel 2d: finalize. Fast path: exactly 16 collected -> copy (set == top-16).
// Else: exact (reference-formula) stable selection among collected; if any
// split hit the 16 cap (~never), full exact rescan.
// grid (NB*NPTS/256), block 256.
// ---------------------------------------------------------------------------
__global__ __launch_bounds__(256) void knnF_kernel(
    const float* __restrict__ p,
    const int* __restrict__ pidx,
    const unsigned* __restrict__ pcnt,
    int* __restrict__ knn_idx)        // [NB][NPTS][16]
{
    const int gid = blockIdx.x * 256 + threadIdx.x;
    const int bb  = gid >> 13;
    const int i   = gid & (NPTS - 1);

    int cnts[NSPLIT_B];
    int total = 0, mx = 0;
    #pragma unroll
    for (int sp = 0; sp < NSPLIT_B; sp++) {
        cnts[sp] = (int)pcnt[((size_t)bb * NSPLIT_B + sp) * NPTS + i];
        total += cnts[sp];
        mx = max(mx, cnts[sp]);
    }
    int* __restrict__ out = knn_idx + (size_t)gid * 16;

    if (mx <= 16 && total == 16) {
        int w = 0;
        for (int sp = 0; sp < NSPLIT_B; sp++) {
            const int* __restrict__ r = pidx + (((size_t)bb * NSPLIT_B + sp) * NPTS + i) * 16;
            for (int e = 0; e < cnts[sp]; e++) out[w++] = r[e];
        }
        return;
    }

    const float qx = p[((size_t)bb * NPTS + i) * 3 + 0];
    const float qy = p[((size_t)bb * NPTS + i) * 3 + 1];
    const float qz = p[((size_t)bb * NPTS + i) * 3 + 2];
    const float sqi = __fadd_rn(__fadd_rn(__fmul_rn(qx, qx), __fmul_rn(qy, qy)),
                                __fmul_rn(qz, qz));
    float ld[16];
    int   li[16];
    #pragma unroll
    for (int s = 0; s < 16; s++) { ld[s] = 3.4e38f; li[s] = 0; }

    if (mx <= 16) {
        // exact stable selection among collected (ascending index order)
        for (int sp = 0; sp < NSPLIT_B; sp++) {
            const int* __restrict__ r = pidx + (((size_t)bb * NSPLIT_B + sp) * NPTS + i) * 16;
            for (int e = 0; e < cnts[sp]; e++) {
                int j = r[e];
                float cx = p[((size_t)bb * NPTS + j) * 3 + 0];
                float cy = p[((size_t)bb * NPTS + j) * 3 + 1];
                float cz = p[((size_t)bb * NPTS + j) * 3 + 2];
                float sqj = __fadd_rn(__fadd_rn(__fmul_rn(cx, cx), __fmul_rn(cy, cy)),
                                      __fmul_rn(cz, cz));
                float dot = __fadd_rn(__fadd_rn(__fmul_rn(qx, cx), __fmul_rn(qy, cy)),
                                      __fmul_rn(qz, cz));
                float d2 = __fsub_rn(__fadd_rn(sqi, sqj), __fmul_rn(2.0f, dot));
                INSERT16(d2, j);
            }
        }
    } else {
        // a split cap was hit (astronomically rare): exact full rescan
        for (int j = 0; j < NPTS; j++) {
            float cx = p[((size_t)bb * NPTS + j) * 3 + 0];
            float cy = p[((size_t)bb * NPTS + j) * 3 + 1];
            float cz = p[((size_t)bb * NPTS + j) * 3 + 2];
            float sqj = __fadd_rn(__fadd_rn(__fmul_rn(cx, cx), __fmul_rn(cy, cy)),
                                  __fmul_rn(cz, cz));
            float dot = __fadd_rn(__fadd_rn(__fmul_rn(qx, cx), __fmul_rn(qy, cy)),
                                  __fmul_rn(qz, cz));
            float d2 = __fsub_rn(__fadd_rn(sqi, sqj), __fmul_rn(2.0f, dot));
            INSERT16(d2, j);
        }
    }
    #pragma unroll
    for (int s = 0; s < 16; s++) out[s] = li[s];
}

// ---------------------------------------------------------------------------
// Kernel 3: fused PE-MLP + attention MLP (bf16 MFMA) + softmax + weighted sum.
// (unchanged from round 6)
// ---------------------------------------------------------------------------
__global__ __launch_bounds__(256) void attn_kernel(
    const float* __restrict__ p,
    const float* __restrict__ qT, const float* __restrict__ kT, const float* __restrict__ vT,
    const int*   __restrict__ knn_idx,
    const float* __restrict__ pe_w1,
    const float* __restrict__ pe_bn_g, const float* __restrict__ pe_bn_b,
    const float* __restrict__ pe_bn_m, const float* __restrict__ pe_bn_v,
    const float* __restrict__ pe_w2, const float* __restrict__ pe_b2,
    const float* __restrict__ bn1g, const float* __restrict__ bn1b,
    const float* __restrict__ bn1m, const float* __restrict__ bn1v,
    const float* __restrict__ at_w1,
    const float* __restrict__ bn2g, const float* __restrict__ bn2b,
    const float* __restrict__ bn2m, const float* __restrict__ bn2v,
    const float* __restrict__ at_w2, const float* __restrict__ at_b2,
    float* __restrict__ y)
{
    const int bb = blockIdx.y;
    const int i0 = blockIdx.x * 8;
    const int t  = threadIdx.x;
    const int w  = t >> 6;
    const int l  = t & 63;
    const int lm = t & 15;
    const int lq = l >> 4;

    __shared__ __align__(16) unsigned short a1s[128 * 128];
    __shared__ __align__(16) float hbuf[3][128];
    __shared__ __align__(16) int   nidx[128];
    __shared__ __align__(16) float sc1[128], sh1[128], sc2[128], sh2[128];
    __shared__ __align__(16) float pw2t[3][128], pb2s[128], ab2s[128];

    float* __restrict__ ybuf = (float*)a1s;

    if (t < 128) {
        int c = t;
        float s1 = bn1g[c] / sqrtf(bn1v[c] + BN_EPS);
        sc1[c] = s1; sh1[c] = bn1b[c] - bn1m[c] * s1;
        float s2 = bn2g[c] / sqrtf(bn2v[c] + BN_EPS);
        sc2[c] = s2; sh2[c] = bn2b[c] - bn2m[c] * s2;
        pw2t[0][c] = pe_w2[c * 3 + 0];
        pw2t[1][c] = pe_w2[c * 3 + 1];
        pw2t[2][c] = pe_w2[c * 3 + 2];
        pb2s[c] = pe_b2[c];
        ab2s[c] = at_b2[c];
    } else {
        int e = t - 128;
        nidx[e] = knn_idx[(bb * NPTS + i0 + (e >> 4)) * 16 + (e & 15)];
    }
    __syncthreads();

    if (t < 128) {
        int pt = t >> 4;
        int j = nidx[t];
        float pix = p[((size_t)bb * NPTS + i0 + pt) * 3 + 0];
        float piy = p[((size_t)bb * NPTS + i0 + pt) * 3 + 1];
        float piz = p[((size_t)bb * NPTS + i0 + pt) * 3 + 2];
        float rx = p[((size_t)bb * NPTS + j) * 3 + 0] - pix;
        float ry = p[((size_t)bb * NPTS + j) * 3 + 1] - piy;
        float rz = p[((size_t)bb * NPTS + j) * 3 + 2] - piz;
        #pragma unroll
        for (int o = 0; o < 3; o++) {
            float hv = pe_w1[o * 3 + 0] * rx + pe_w1[o * 3 + 1] * ry + pe_w1[o * 3 + 2] * rz;
            float sc = pe_bn_g[o] / sqrtf(pe_bn_v[o] + BN_EPS);
            float sh = pe_bn_b[o] - pe_bn_m[o] * sc;
            hbuf[o][t] = fmaxf(hv * sc + sh, 0.0f);
        }
    }
    __syncthreads();

    {
        const int c0 = 2 * l, c1 = 2 * l + 1;
        const float s1a = sc1[c0], b1a = sh1[c0], s1b = sc1[c1], b1b = sh1[c1];
        const float pwa0 = pw2t[0][c0], pwa1 = pw2t[1][c0], pwa2 = pw2t[2][c0], pba = pb2s[c0];
        const float pwb0 = pw2t[0][c1], pwb1 = pw2t[1][c1], pwb2 = pw2t[2][c1], pbb = pb2s[c1];
        unsigned* a1u = (unsigned*)a1s;
        for (int it = 0; it < 32; ++it) {
            int col = w + 4 * it;
            int pt  = col >> 4;
            int j   = nidx[col];
            float2 qv2 = *(const float2*)&qT[((size_t)(bb * NPTS + i0 + pt)) * NC + c0];
            float2 kv2 = *(const float2*)&kT[((size_t)(bb * NPTS + j)) * NC + c0];
            float h0 = hbuf[0][col], h1 = hbuf[1][col], h2 = hbuf[2][col];
            float nra = pwa0 * h0 + pwa1 * h1 + pwa2 * h2 + pba;
            float nrb = pwb0 * h0 + pwb1 * h1 + pwb2 * h2 + pbb;
            float a0 = fmaxf((qv2.x - kv2.x + nra) * s1a + b1a, 0.0f);
            float a1v = fmaxf((qv2.y - kv2.y + nrb) * s1b + b1b, 0.0f);
            a1u[col * 64 + (l ^ ((col & 7) << 2))] = pack2bf(a0, a1v);
        }
    }

    v8s wf[2][4];
    #pragma unroll
    for (int rt = 0; rt < 2; rt++)
        #pragma unroll
        for (int ks = 0; ks < 4; ks++)
            wf[rt][ks] = load_wfrag_bf16(at_w1 + (size_t)(w * 32 + rt * 16 + lm) * NC + ks * 32 + lq * 8);

    __syncthreads();

    v4f acc[2][8];
    #pragma unroll
    for (int rt = 0; rt < 2; rt++)
        #pragma unroll
        for (int ct = 0; ct < 8; ct++) acc[rt][ct] = (v4f)0.0f;

    #pragma unroll
    for (int ct = 0; ct < 8; ct++) {
        const int col = ct * 16 + lm;
        const int sw8 = (col & 7) << 3;
        #pragma unroll
        for (int ks = 0; ks < 4; ks++) {
            v8s b = *(const v8s*)&a1s[col * 128 + ((ks * 32 + lq * 8) ^ sw8)];
            acc[0][ct] = __builtin_amdgcn_mfma_f32_16x16x32_bf16(wf[0][ks], b, acc[0][ct], 0, 0, 0);
            acc[1][ct] = __builtin_amdgcn_mfma_f32_16x16x32_bf16(wf[1][ks], b, acc[1][ct], 0, 0, 0);
        }
    }
    __syncthreads();

    #pragma unroll
    for (int rt = 0; rt < 2; rt++) {
        const int r0 = w * 32 + rt * 16 + lq * 4;
        float4 scv = *(const float4*)&sc2[r0];
        float4 shv = *(const float4*)&sh2[r0];
        #pragma unroll
        for (int ct = 0; ct < 8; ct++) {
            const int col = ct * 16 + lm;
            v4f v = acc[rt][ct];
            float x0 = fmaxf(v[0] * scv.x + shv.x, 0.0f);
            float x1 = fmaxf(v[1] * scv.y + shv.y, 0.0f);
            float x2 = fmaxf(v[2] * scv.z + shv.z, 0.0f);
            float x3 = fmaxf(v[3] * scv.w + shv.w, 0.0f);
            *(uint2*)&a1s[col * 128 + (r0 ^ ((col & 7) << 3))] =
                make_uint2(pack2bf(x0, x1), pack2bf(x2, x3));
        }
    }

    #pragma unroll
    for (int rt = 0; rt < 2; rt++)
        #pragma unroll
        for (int ks = 0; ks < 4; ks++)
            wf[rt][ks] = load_wfrag_bf16(at_w2 + (size_t)(w * 32 + rt * 16 + lm) * NC + ks * 32 + lq * 8);

    __syncthreads();

    #pragma unroll
    for (int rt = 0; rt < 2; rt++)
        #pragma unroll
        for (int ct = 0; ct < 8; ct++) acc[rt][ct] = (v4f)0.0f;

    #pragma unroll
    for (int ct = 0; ct < 8; ct++) {
        const int col = ct * 16 + lm;
        const int sw8 = (col & 7) << 3;
        #pragma unroll
        for (int ks = 0; ks < 4; ks++) {
            v8s b = *(const v8s*)&a1s[col * 128 + ((ks * 32 + lq * 8) ^ sw8)];
            acc[0][ct] = __builtin_amdgcn_mfma_f32_16x16x32_bf16(b, wf[0][ks], acc[0][ct], 0, 0, 0);
            acc[1][ct] = __builtin_amdgcn_mfma_f32_16x16x32_bf16(b, wf[1][ks], acc[1][ct], 0, 0, 0);
        }
    }
    __syncthreads();

    #pragma unroll
    for (int ct = 0; ct < 8; ct++) {
        const int colb = ct * 16 + lq * 4;
        float4 h0 = *(const float4*)&hbuf[0][colb];
        float4 h1 = *(const float4*)&hbuf[1][colb];
        float4 h2 = *(const float4*)&hbuf[2][colb];
        int j0 = nidx[colb + 0], j1 = nidx[colb + 1];
        int j2 = nidx[colb + 2], j3 = nidx[colb + 3];
        #pragma unroll
        for (int rt = 0; rt < 2; rt++) {
            const int c = w * 32 + rt * 16 + lm;
            const float pw0 = pw2t[0][c], pw1 = pw2t[1][c], pw2v = pw2t[2][c];
            const float pb = pb2s[c], b2 = ab2s[c];
            v4f lg = acc[rt][ct];
            float v0 = vT[((size_t)(bb * NPTS + j0)) * NC + c];
            float v1 = vT[((size_t)(bb * NPTS + j1)) * NC + c];
            float v2 = vT[((size_t)(bb * NPTS + j2)) * NC + c];
            float v3 = vT[((size_t)(bb * NPTS + j3)) * NC + c];
            float e0 = __expf(lg[0] + b2);
            float e1 = __expf(lg[1] + b2);
            float e2 = __expf(lg[2] + b2);
            float e3 = __expf(lg[3] + b2);
            float n0 = pw0 * h0.x + pw1 * h1.x + pw2v * h2.x + pb;
            float n1 = pw0 * h0.y + pw1 * h1.y + pw2v * h2.y + pb;
            float n2 = pw0 * h0.z + pw1 * h1.z + pw2v * h2.z + pb;
            float n3 = pw0 * h0.w + pw1 * h1.w + pw2v * h2.w + pb;
            float se = (e0 + e1) + (e2 + e3);
            float pr = (e0 * (v0 + n0) + e1 * (v1 + n1)) + (e2 * (v2 + n2) + e3 * (v3 + n3));
            se += __shfl_xor(se, 16); pr += __shfl_xor(pr, 16);
            se += __shfl_xor(se, 32); pr += __shfl_xor(pr, 32);
            if (lq == 0) ybuf[c * 12 + ct] = pr / se;
        }
    }
    __syncthreads();

    {
        int c = t >> 1, half = t & 1;
        float4 o = *(const float4*)&ybuf[c * 12 + half * 4];
        *(float4*)&y[((size_t)bb * NC + c) * NPTS + i0 + half * 4] = o;
    }
}

// ---------------------------------------------------------------------------
extern "C" void kernel_launch(void* const* d_in, const int* in_sizes, int n_in,
                              void* d_out, int out_size, void* d_ws, size_t ws_size,
                              hipStream_t stream) {
    const float* p     = (const float*)d_in[0];
    const float* x     = (const float*)d_in[1];
    const float* wq    = (const float*)d_in[2];
    const float* bq    = (const float*)d_in[3];
    const float* wk    = (const float*)d_in[4];
    const float* bk    = (const float*)d_in[5];
    const float* wv    = (const float*)d_in[6];
    const float* bv    = (const float*)d_in[7];
    const float* pe_w1 = (const float*)d_in[8];
    const float* pe_bn_g = (const float*)d_in[9];
    const float* pe_bn_b = (const float*)d_in[10];
    const float* pe_bn_m = (const float*)d_in[11];
    const float* pe_bn_v = (const float*)d_in[12];
    const float* pe_w2 = (const float*)d_in[13];
    const float* pe_b2 = (const float*)d_in[14];
    const float* bn1g  = (const float*)d_in[15];
    const float* bn1b  = (const float*)d_in[16];
    const float* bn1m  = (const float*)d_in[17];
    const float* bn1v  = (const float*)d_in[18];
    const float* at_w1 = (const float*)d_in[19];
    const float* bn2g  = (const float*)d_in[20];
    const float* bn2b  = (const float*)d_in[21];
    const float* bn2m  = (const float*)d_in[22];
    const float* bn2v  = (const float*)d_in[23];
    const float* at_w2 = (const float*)d_in[24];
    const float* at_b2 = (const float*)d_in[25];
    float* out = (float*)d_out;

    // workspace (25 MB), X = ws + 1MB (24 MB region). All kNN scratch aliases
    // the qT/kT/vT region; every kNN kernel completes before qkv writes.
    //   partd [2][32][8192][8] f32 = 16.8MB at X       (knnA -> knnM)
    //   pidx  [2][16][8192][16] i32 = 16.8MB at X      (knnB -> knnF, after knnM)
    //   pcnt  [2][16][8192] u32 = 1.05MB at X + 18MB   (knnB -> knnF)
    //   thr   [2][8192] f32 = 64KB at X + 20MB         (knnM -> knnB)
    char* base = (char*)d_ws;
    int*   idx   = (int*)base;
    char*  X     = base + (1u << 20);
    float* qT    = (float*)X;
    float* kT    = qT + (size_t)NB * NPTS * NC;
    float* vT    = kT + (size_t)NB * NPTS * NC;
    float* partd = (float*)X;
    int*   pidx  = (int*)X;
    unsigned* pcnt = (unsigned*)(X + (size_t)18 * (1u << 20));
    float* thr   = (float*)(X + (size_t)20 * (1u << 20));

    knnA_kernel<<<dim3(NPTS / 512, NSPLIT_A, NB), 256, 0, stream>>>(p, partd);
    knnM_kernel<<<dim3(NB * NPTS / 256), 256, 0, stream>>>(partd, thr);
    knnB_kernel<<<dim3(NPTS / 256, NSPLIT_B, NB), 256, 0, stream>>>(p, thr, pidx, pcnt);
    knnF_kernel<<<dim3(NB * NPTS / 256), 256, 0, stream>>>(p, pidx, pcnt, idx);
    qkv_kernel<<<dim3(NPTS / 64, NB), 256, 0, stream>>>(
        x, wq, bq, wk, bk, wv, bv, qT, kT, vT);
    attn_kernel<<<dim3(NPTS / 8, NB), 256, 0, stream>>>(
        p, qT, kT, vT, idx,
        pe_w1, pe_bn_g, pe_bn_b, pe_bn_m, pe_bn_v, pe_w2, pe_b2,
        bn1g, bn1b, bn1m, bn1v, at_w1,
        bn2g, bn2b, bn2m, bn2v, at_w2, at_b2, out);
}